// Round 17
// baseline (860.976 us; speedup 1.0000x reference)
//
#include <hip/hip_runtime.h>
#include <stdint.h>

// ---- problem constants ----
#define NB 2
#define NL 1024
#define ND 2048
#define NE 4096
#define NN 16
#define NR 128
#define NKC 4
#define NBL (NB*NL)          // 2048 rows
#define EPSV 1e-5f
#define SEG_T 256            // scan L-split segment length (4 segments)
#define SCAN_T 32            // LDS chunk within a segment (small -> high occupancy)

typedef __attribute__((ext_vector_type(4))) float f32x4;
typedef __attribute__((ext_vector_type(8))) short short8;
typedef __attribute__((ext_vector_type(8))) unsigned short ushort8;
typedef __attribute__((ext_vector_type(4))) unsigned short ushort4_t;
typedef __attribute__((ext_vector_type(2))) unsigned short ushort2_t;

__device__ __forceinline__ unsigned short f2bf(float f) {
  union { float f; unsigned u; } v; v.f = f;
  unsigned r = v.u + 0x7FFFu + ((v.u >> 16) & 1u);   // RNE
  return (unsigned short)(r >> 16);
}

__device__ __forceinline__ float bf2f(unsigned short u) {
  union { unsigned u; float f; } v; v.u = (unsigned)u << 16; return v.f;
}

__device__ __forceinline__ void load_lds16(const void* g, void* l) {
  __builtin_amdgcn_global_load_lds((const __attribute__((address_space(1))) void*)g,
                                   (__attribute__((address_space(3))) void*)l,
                                   16, 0, 0);
}

// LDS swizzle for gemm_bt tiles (measured neutral in r13 — kept, harmless).
__device__ __forceinline__ int swzmask(int row) {  // element-offset mask (x8)
  return ((row ^ (row >> 2)) & 3) * 8;
}

template<int CTRL>
__device__ __forceinline__ float dpp_mov(float v) {
  return __int_as_float(__builtin_amdgcn_update_dpp(
      0, __float_as_int(v), CTRL, 0xF, 0xF, true));
}

// ---------------- RMSNorm: resid[row,0:2048] -> rn_bf16 ----------------
__global__ void rmsnorm_kernel(const float* __restrict__ resid,
                               const float* __restrict__ nw,
                               unsigned short* __restrict__ rn) {
  int row = blockIdx.x;
  int tid = threadIdx.x;                 // 256 threads, 8 f32 each
  const float* r = resid + (size_t)row * ND;
  f32x4 v0 = *(const f32x4*)(r + tid * 8);
  f32x4 v1 = *(const f32x4*)(r + tid * 8 + 4);
  float vals[8];
#pragma unroll
  for (int i = 0; i < 4; ++i) { vals[i] = v0[i]; vals[4 + i] = v1[i]; }
  float ss = 0.f;
#pragma unroll
  for (int i = 0; i < 8; ++i) ss += vals[i] * vals[i];
  for (int o = 32; o > 0; o >>= 1) ss += __shfl_down(ss, o);
  __shared__ float ps[4];
  if ((tid & 63) == 0) ps[tid >> 6] = ss;
  __syncthreads();
  float tot = ps[0] + ps[1] + ps[2] + ps[3];
  float scale = rsqrtf(tot / (float)ND + EPSV);
  ushort8 o8;
#pragma unroll
  for (int i = 0; i < 8; ++i) o8[i] = f2bf(vals[i] * scale * nw[tid * 8 + i]);
  *(ushort8*)(rn + (size_t)row * ND + tid * 8) = o8;
}

// ---------------- generic f32 -> bf16 cast (8 elems/thread) ----------------
__global__ void cast_bf16_kernel(const float* __restrict__ in,
                                 unsigned short* __restrict__ out, int n8) {
  int i = blockIdx.x * blockDim.x + threadIdx.x;
  if (i >= n8) return;
  f32x4 a = *(const f32x4*)(in + (size_t)i * 8);
  f32x4 b = *(const f32x4*)(in + (size_t)i * 8 + 4);
  ushort8 o;
#pragma unroll
  for (int j = 0; j < 4; ++j) { o[j] = f2bf(a[j]); o[4 + j] = f2bf(b[j]); }
  *(ushort8*)(out + (size_t)i * 8) = o;
}

// ---- build concatenated [256 x 4096] bf16 weight: rows 0-127 wd1, 128-143 wB, 144-159 wC, rest 0
__global__ void build_wcat_kernel(const float* __restrict__ wd1,
                                  const float* __restrict__ wB,
                                  const float* __restrict__ wC,
                                  unsigned short* __restrict__ out) {
  int i = blockIdx.x * blockDim.x + threadIdx.x;   // total 256*4096/8 = 131072
  if (i >= 256 * NE / 8) return;
  int col8 = i & (NE / 8 - 1);
  int row = i >> 9;
  const float* src = nullptr; int srow = 0;
  if (row < 128)      { src = wd1; srow = row; }
  else if (row < 144) { src = wB;  srow = row - 128; }
  else if (row < 160) { src = wC;  srow = row - 144; }
  ushort8 o;
  if (src) {
    f32x4 a = *(const f32x4*)(src + (size_t)srow * NE + col8 * 8);
    f32x4 b = *(const f32x4*)(src + (size_t)srow * NE + col8 * 8 + 4);
#pragma unroll
    for (int j = 0; j < 4; ++j) { o[j] = f2bf(a[j]); o[4 + j] = f2bf(b[j]); }
  } else {
#pragma unroll
    for (int j = 0; j < 8; ++j) o[j] = 0;
  }
  *(ushort8*)(out + (size_t)row * NE + col8 * 8) = o;
}

// ======== 256x256 GEMM, 2-buffer ring (64KB LDS -> 2 blocks/CU), fused skip+in ========
// r17: occupancy play. Stage tile t+1 into buf (t+1)&1 (never the buffer being
// read -> race-free); one stage-issue per quadrant phase; vmcnt(0)+barrier at
// each K-tile boundary (m97 pattern). Cross-block TLP (2 blocks/CU = 4
// waves/SIMD) covers the boundary drain (m114 overlap).
__global__ __launch_bounds__(512, 4)
void gemm256_fused(const unsigned short* __restrict__ A,
                   const unsigned short* __restrict__ B,
                   float* __restrict__ Gout,
                   unsigned short* __restrict__ Xout) {
  const int K = 2048, NH = K / 32;   // 64 K-tiles of BK=32
  __shared__ unsigned short Asl[2][256 * 32];   // 16KB each
  __shared__ unsigned short Bsl[2][256 * 32];
  int tid = threadIdx.x;
  int w = tid >> 6, lane = tid & 63;
  int wm = w >> 2, wn = w & 3;
  int lr = lane & 15, kg8 = (lane >> 4) * 8;
  // XCD remap (r16, kept: +4% measured): xcd = L&7 owns 4 n-tiles x 8 m-tiles.
  int L = blockIdx.x + gridDim.x * blockIdx.y;
  int xcd = L & 7, p = L >> 3;
  int m0 = (p >> 2) * 256;
  int n0 = (xcd * 4 + (p & 3)) * 256;

  // staging: thread covers row tid>>2 (128 rows/issue), 16B-col tid&3.
  int srow = tid >> 2, scol = (tid & 3) * 8;
  const unsigned short* ga = A + (size_t)(m0 + srow) * K + scol;
  const unsigned short* gb = B + (size_t)(n0 + srow) * K + scol;

  // issue j: 0=A rows 0-127, 1=A rows 128-255, 2=B rows 0-127, 3=B rows 128-255.
  auto stageQ = [&](int buf, int t, int j) {
    int k0 = t * 32;
    if (j < 2)
      load_lds16(ga + (size_t)j * 128 * K + k0,
                 (char*)&Asl[buf][0] + j * 8192 + w * 1024);
    else
      load_lds16(gb + (size_t)(j - 2) * 128 * K + k0,
                 (char*)&Bsl[buf][0] + (j - 2) * 8192 + w * 1024);
  };

  f32x4 acc[8][4];
#pragma unroll
  for (int i = 0; i < 8; ++i)
#pragma unroll
    for (int j = 0; j < 4; ++j) acc[i][j] = (f32x4){0.f, 0.f, 0.f, 0.f};

  // prologue: stage tile 0 into buf 0
#pragma unroll
  for (int j = 0; j < 4; ++j) stageQ(0, 0, j);

  int arow = wm * 128 + lr;
  int brow = wn * 64 + lr;

  for (int t = 0; t < NH; ++t) {
    int buf = t & 1;
    asm volatile("s_waitcnt vmcnt(0)" ::: "memory");  // tile t fully landed
    __builtin_amdgcn_s_barrier();                      // all waves see it; prev
                                                       // tile's reads done
    const unsigned short* As_ = &Asl[buf][0];
    const unsigned short* Bs_ = &Bsl[buf][0];
    bool st = (t + 1 < NH);
    int nbuf = buf ^ 1;
    short8 a[8], b[4];
    // ---- quadrant m0 x n0 ----
#pragma unroll
    for (int i = 0; i < 4; ++i)
      a[i] = *(const short8*)&As_[(arow + i * 16) * 32 + kg8];
#pragma unroll
    for (int j = 0; j < 2; ++j)
      b[j] = *(const short8*)&Bs_[(brow + j * 16) * 32 + kg8];
    if (st) stageQ(nbuf, t + 1, 0);
    __builtin_amdgcn_s_setprio(1);
#pragma unroll
    for (int i = 0; i < 4; ++i)
#pragma unroll
      for (int j = 0; j < 2; ++j)
        acc[i][j] = __builtin_amdgcn_mfma_f32_16x16x32_bf16(a[i], b[j], acc[i][j], 0, 0, 0);
    __builtin_amdgcn_s_setprio(0);
    // ---- quadrant m0 x n1 ----
#pragma unroll
    for (int j = 2; j < 4; ++j)
      b[j] = *(const short8*)&Bs_[(brow + j * 16) * 32 + kg8];
    if (st) stageQ(nbuf, t + 1, 1);
    __builtin_amdgcn_s_setprio(1);
#pragma unroll
    for (int i = 0; i < 4; ++i)
#pragma unroll
      for (int j = 2; j < 4; ++j)
        acc[i][j] = __builtin_amdgcn_mfma_f32_16x16x32_bf16(a[i], b[j], acc[i][j], 0, 0, 0);
    __builtin_amdgcn_s_setprio(0);
    // ---- quadrant m1 x n1 ----
#pragma unroll
    for (int i = 4; i < 8; ++i)
      a[i] = *(const short8*)&As_[(arow + i * 16) * 32 + kg8];
    if (st) stageQ(nbuf, t + 1, 2);
    __builtin_amdgcn_s_setprio(1);
#pragma unroll
    for (int i = 4; i < 8; ++i)
#pragma unroll
      for (int j = 2; j < 4; ++j)
        acc[i][j] = __builtin_amdgcn_mfma_f32_16x16x32_bf16(a[i], b[j], acc[i][j], 0, 0, 0);
    __builtin_amdgcn_s_setprio(0);
    // ---- quadrant m1 x n0 (b[0],b[1] still live) ----
    if (st) stageQ(nbuf, t + 1, 3);
    __builtin_amdgcn_s_setprio(1);
#pragma unroll
    for (int i = 4; i < 8; ++i)
#pragma unroll
      for (int j = 0; j < 2; ++j)
        acc[i][j] = __builtin_amdgcn_mfma_f32_16x16x32_bf16(a[i], b[j], acc[i][j], 0, 0, 0);
    __builtin_amdgcn_s_setprio(0);
  }

  // epilogue: C/D col=lane&15, row=(lane>>4)*4+reg (verified layout)
  int rbase = m0 + wm * 128 + (lane >> 4) * 4;
  int cbase = n0 + wn * 64 + (lane & 15);
  bool isg = (n0 < 4096);
#pragma unroll
  for (int mf = 0; mf < 8; ++mf) {
#pragma unroll
    for (int nf = 0; nf < 4; ++nf) {
      int col = cbase + nf * 16;
#pragma unroll
      for (int rr = 0; rr < 4; ++rr) {
        int row = rbase + mf * 16 + rr;
        float v = acc[mf][nf][rr];
        if (isg) Gout[(size_t)row * 4096 + col] = v / (1.f + __expf(-v));
        else     Xout[(size_t)row * 4096 + (col - 4096)] = f2bf(v);
      }
    }
  }
}

// ---------------- bf16 MFMA GEMM, 3-slot ring pipeline (T3+T4+T5) ----------------
// MODE 0: f32 partials (split-K via z); MODE 1: softplus->bf16.
template<int MODE>
__global__ __launch_bounds__(256)
void gemm_bt(const unsigned short* __restrict__ A,
             const unsigned short* __restrict__ B,
             float* __restrict__ C,
             int M, int N, int K, int ksteps_per_z,
             const float* __restrict__ bias,
             unsigned short* __restrict__ out2) {
  __shared__ unsigned short As[3][128 * 32];
  __shared__ unsigned short Bs[3][128 * 32];
  int tid = threadIdx.x;
  int w = tid >> 6, lane = tid & 63;
  int m0 = blockIdx.y * 128, n0 = blockIdx.x * 128;
  int kz0 = blockIdx.z * ksteps_per_z * 32;
  if (MODE == 0) C += (size_t)blockIdx.z * M * N;
  const int NH = ksteps_per_z;

  f32x4 acc[4][4];
#pragma unroll
  for (int i = 0; i < 4; ++i)
#pragma unroll
    for (int j = 0; j < 4; ++j) acc[i][j] = (f32x4){0.f, 0.f, 0.f, 0.f};

  int wm = w >> 1, wn = w & 1;
  int lr = lane & 15, kg = lane >> 4;

  int fe0 = (w) * 512 + lane * 8;
  int fe1 = (4 + w) * 512 + lane * 8;
  int r0 = fe0 >> 5, c0 = fe0 & 31;
  int r1 = fe1 >> 5, c1 = fe1 & 31;
  int sc0 = c0 ^ swzmask(r0);
  int sc1 = c1 ^ swzmask(r1);
  const unsigned short* Ag0 = A + (size_t)(m0 + r0) * K + sc0 + kz0;
  const unsigned short* Ag1 = A + (size_t)(m0 + r1) * K + sc1 + kz0;
  const unsigned short* Bg0 = B + (size_t)(n0 + r0) * K + sc0 + kz0;
  const unsigned short* Bg1 = B + (size_t)(n0 + r1) * K + sc1 + kz0;

  auto stage = [&](int h) {
    int slot = h % 3, kk = h * 32;
    load_lds16(Ag0 + kk, &As[slot][(w) * 512]);
    load_lds16(Ag1 + kk, &As[slot][(4 + w) * 512]);
    load_lds16(Bg0 + kk, &Bs[slot][(w) * 512]);
    load_lds16(Bg1 + kk, &Bs[slot][(4 + w) * 512]);
  };

  stage(0);
  if (NH > 1) stage(1);

  int kgs = (kg * 8) ^ swzmask(lr);

  for (int h = 0; h < NH; ++h) {
    int slot = h % 3;
    __builtin_amdgcn_s_barrier();
    if (h + 2 < NH) stage(h + 2);
    int rem = NH - 1 - h;
    if (rem >= 2)      { asm volatile("s_waitcnt vmcnt(8)" ::: "memory"); }
    else if (rem == 1) { asm volatile("s_waitcnt vmcnt(4)" ::: "memory"); }
    else               { asm volatile("s_waitcnt vmcnt(0)" ::: "memory"); }
    __builtin_amdgcn_s_barrier();
    short8 a[4], b[4];
#pragma unroll
    for (int i = 0; i < 4; ++i)
      a[i] = *(const short8*)&As[slot][(wm * 64 + i * 16 + lr) * 32 + kgs];
#pragma unroll
    for (int j = 0; j < 4; ++j)
      b[j] = *(const short8*)&Bs[slot][(wn * 64 + j * 16 + lr) * 32 + kgs];
    __builtin_amdgcn_s_setprio(1);
#pragma unroll
    for (int i = 0; i < 4; ++i)
#pragma unroll
      for (int j = 0; j < 4; ++j)
        acc[i][j] = __builtin_amdgcn_mfma_f32_16x16x32_bf16(a[i], b[j], acc[i][j], 0, 0, 0);
    __builtin_amdgcn_s_setprio(0);
  }

#pragma unroll
  for (int i = 0; i < 4; ++i) {
#pragma unroll
    for (int j = 0; j < 4; ++j) {
      int rbase = m0 + wm * 64 + i * 16 + kg * 4;
      int col = n0 + wn * 64 + j * 16 + lr;
#pragma unroll
      for (int r = 0; r < 4; ++r) {
        float v = acc[i][j][r];
        if (MODE == 0) {
          C[(size_t)(rbase + r) * N + col] = v;
        } else {
          float t = v + bias[col];
          ((unsigned short*)C)[(size_t)(rbase + r) * N + col] =
              f2bf((t > 20.f) ? t : log1pf(__expf(t)));
        }
      }
    }
  }
  (void)out2;
}

// ---------------- out reduction: out = resid + sum_z part[z] ----------------
__global__ void reduce_out_kernel(const float* __restrict__ part,
                                  const float* __restrict__ resid,
                                  float* __restrict__ out) {
  size_t base = ((size_t)blockIdx.x * blockDim.x + threadIdx.x) * 4;
  if (base >= (size_t)NBL * ND) return;
  f32x4 r = *(const f32x4*)(resid + base);
#pragma unroll
  for (int z = 0; z < 4; ++z)
    r += *(const f32x4*)(part + (size_t)z * NBL * ND + base);
  *(f32x4*)(out + base) = r;
}

// ---------------- depthwise causal conv (K=4) + SiLU -> bf16 ----------------
__global__ void conv_silu_kernel(const unsigned short* __restrict__ xin,
                                 const float* __restrict__ cw,
                                 const float* __restrict__ cb,
                                 unsigned short* __restrict__ xbf) {
  size_t idx = (size_t)blockIdx.x * blockDim.x + threadIdx.x;
  if (idx >= (size_t)NB * NL * NE) return;
  int e = (int)(idx & (NE - 1));
  int r = (int)(idx >> 12);            // b*NL + l
  int l = r & (NL - 1);
  float acc = cb[e];
#pragma unroll
  for (int k = 0; k < NKC; ++k) {
    int ls = l - 3 + k;
    if (ls >= 0) acc += bf2f(xin[(size_t)(r - 3 + k) * NE + e]) * cw[e * 4 + k];
  }
  float s = acc / (1.f + __expf(-acc));
  xbf[idx] = f2bf(s);
}

// ---------------- reduce split-K partials of the concat GEMM (16 slices) ----------------
__global__ void reduce_tcat_kernel(const float* __restrict__ part,
                                   unsigned short* __restrict__ tbf,
                                   float* __restrict__ bc) {
  int idx = blockIdx.x * blockDim.x + threadIdx.x;
  if (idx >= NBL * 160) return;
  int m = idx / 160, c = idx - m * 160;
  float s = 0.f;
#pragma unroll
  for (int z = 0; z < 16; ++z) s += part[(size_t)z * NBL * 256 + (size_t)m * 256 + c];
  if (c < 128) tbf[m * 128 + c] = f2bf(s);
  else if (c < 144) bc[m * 32 + (c - 128)] = s;
  else bc[m * 32 + 16 + (c - 144)] = s;
}

// ======== selective scan, 4-way L-split, SCAN_T=32 (high occupancy) ========
__global__ __launch_bounds__(256)
void scan1_kernel(const unsigned short* __restrict__ delta_bf,
                  const unsigned short* __restrict__ x_bf,
                  const float* __restrict__ bc,
                  const float* __restrict__ gf,
                  const float* __restrict__ A_log,
                  const float* __restrict__ W_D,
                  unsigned short* __restrict__ yg,
                  float* __restrict__ fin,
                  float* __restrict__ dtot) {
  __shared__ unsigned short dxl[2][SCAN_T][2][16];  // [buf][t][{d,x}][e]  4KB
  __shared__ float gl[2][SCAN_T][16];               // 4KB
  __shared__ float BCl[2][SCAN_T][32];              // 8KB
  __shared__ float yl2[SCAN_T][16][2];              // 4KB
  __shared__ float wdl[16];
  int tid = threadIdx.x;
  int n = tid & 15, el = tid >> 4;
  int w = tid >> 6, lane = tid & 63;
  int e0 = blockIdx.x * 16;
  int b = blockIdx.y >> 2, seg = blockIdx.y & 3;
  int e = e0 + el;
  float A2 = -__expf(A_log[e * 16 + n]) * 1.44269504f;
  if (tid < 16) wdl[tid] = W_D[e0 + tid];
  float h = 0.f, cum = 0.f;

  const unsigned short* gdl = delta_bf + (size_t)b * NL * NE + e0;
  const unsigned short* gx  = x_bf + (size_t)b * NL * NE + e0;
  const float* gg  = gf + (size_t)b * NL * 4096 + e0;
  const float* gBC = bc + (size_t)b * NL * 32;

  const unsigned short* dxsrc = ((lane >> 1) & 1) ? gx : gdl;  // waves 0,1
  int dxrow = (w & 1) * 16 + (lane >> 2);
  int dxcol = (lane & 1) * 8;
  int grow = (w & 1) * 16 + (lane >> 2);                        // waves 2,3
  int gcol = (lane & 3) * 4;
  int bcrow = w * 8 + (lane >> 3);                              // all waves
  int bccol = (lane & 7) * 4;
  int nloads = (seg == 0 || w < 2) ? 2 : 1;

  auto stage = [&](int buf, int c) {
    int l0 = seg * SEG_T + c * SCAN_T;
    if (w < 2)
      load_lds16(dxsrc + (size_t)(l0 + dxrow) * NE + dxcol, &dxl[buf][(w & 1) * 16][0][0]);
    else if (seg == 0)
      load_lds16(gg + (size_t)(l0 + grow) * 4096 + gcol, &gl[buf][(w & 1) * 16][0]);
    load_lds16(gBC + (size_t)(l0 + bcrow) * 32 + bccol, &BCl[buf][w * 8][0]);
  };

  stage(0, 0);
  const int nch = SEG_T / SCAN_T;  // 8
  for (int c = 0; c < nch; ++c) {
    int cur = c & 1;
    if (c + 1 < nch) {
      stage(cur ^ 1, c + 1);
      if (nloads == 2) { asm volatile("s_waitcnt vmcnt(2)" ::: "memory"); }
      else             { asm volatile("s_waitcnt vmcnt(1)" ::: "memory"); }
    } else {
      asm volatile("s_waitcnt vmcnt(0)" ::: "memory");
    }
    __syncthreads();
    const unsigned short (*dxc)[2][16] = dxl[cur];
    const float (*BCc)[32] = BCl[cur];
#pragma unroll 8
    for (int t = 0; t < SCAN_T; ++t) {
      float dc = bf2f(dxc[t][0][el]);
      float xc = bf2f(dxc[t][1][el]);
      float Bc = BCc[t][n];
      float Cc = BCc[t][16 + n];
      cum += dc;
      float a = dc * A2, ed;
      asm("v_exp_f32 %0, %1" : "=v"(ed) : "v"(a));   // exp2(d*A*log2e)
      h = ed * h + (dc * xc) * Bc;
      float p = h * Cc;
      p += dpp_mov<0xB1>(p);    // xor1
      p += dpp_mov<0x4E>(p);    // xor2
      p += dpp_mov<0x141>(p);   // half-mirror -> lanes 0,8 hold 8-group sums
      if ((n & 7) == 0) yl2[t][el][n >> 3] = p;
    }
    __syncthreads();
    {
      int t = tid >> 3, part = tid & 7;   // 2 e's per thread
      int l0 = seg * SEG_T + c * SCAN_T;
      ushort2_t o;
#pragma unroll
      for (int j = 0; j < 2; ++j) {
        int ee = part * 2 + j;
        float xv = bf2f(dxc[t][1][ee]);
        float y = yl2[t][ee][0] + yl2[t][ee][1] + xv * wdl[ee];
        if (seg == 0) y *= gl[cur][t][ee];
        o[j] = f2bf(y);
      }
      *(ushort2_t*)(yg + (size_t)(b * NL + l0 + t) * NE + e0 + part * 2) = o;
    }
    __syncthreads();
  }
  fin[(size_t)((seg * 2 + b) * 4096 + e) * 16 + n] = h;
  if (n == 0) dtot[(size_t)(seg * 2 + b) * 4096 + e] = cum;
}

// K2: fixup for segments 1..3
__global__ __launch_bounds__(256)
void scan2_kernel(const unsigned short* __restrict__ delta_bf,
                  unsigned short* __restrict__ yg,
                  const float* __restrict__ bc,
                  const float* __restrict__ gf,
                  const float* __restrict__ A_log,
                  const float* __restrict__ fin,
                  const float* __restrict__ dtot) {
  __shared__ unsigned short dl[2][SCAN_T][16];      // 2KB
  __shared__ unsigned short ypl[2][SCAN_T][16];     // 2KB
  __shared__ float Cl[2][SCAN_T][16];               // 4KB
  __shared__ float gl2[2][SCAN_T][16];              // 4KB
  __shared__ float ycl[SCAN_T][16][2];              // 4KB
  int tid = threadIdx.x;
  int n = tid & 15, el = tid >> 4;
  int w = tid >> 6, lane = tid & 63;
  int e0 = blockIdx.x * 16;
  int b = blockIdx.y / 3, seg = 1 + blockIdx.y % 3;
  int e = e0 + el;
  float A2 = -__expf(A_log[e * 16 + n]) * 1.44269504f;
  float h = fin[(size_t)(b * 4096 + e) * 16 + n];           // seg 0 final
  for (int s2 = 1; s2 < seg; ++s2) {
    float dt = dtot[(size_t)(s2 * 2 + b) * 4096 + e];
    float a = A2 * dt, pw;
    asm("v_exp_f32 %0, %1" : "=v"(pw) : "v"(a));
    h = fin[(size_t)((s2 * 2 + b) * 4096 + e) * 16 + n] + pw * h;
  }

  const unsigned short* gd = delta_bf + (size_t)b * NL * NE + e0;
  unsigned short* gy = yg + (size_t)b * NL * NE + e0;
  const float* gg  = gf + (size_t)b * NL * 4096 + e0;
  const float* gBC = bc + (size_t)b * NL * 32;

  int dyrow = lane >> 1;
  int dycol = (lane & 1) * 8;
  int crow = (w & 1) * 16 + (lane >> 2);
  int ccol = 16 + (lane & 3) * 4;
  int grow = (w & 1) * 16 + (lane >> 2);
  int gcol = (lane & 3) * 4;
  int nloads = (w < 2) ? 2 : 1;

  auto stage = [&](int buf, int c) {
    int l0 = seg * SEG_T + c * SCAN_T;
    if (w == 0)      load_lds16(gd + (size_t)(l0 + dyrow) * NE + dycol, &dl[buf][0][0]);
    else if (w == 1) load_lds16(gy + (size_t)(l0 + dyrow) * NE + dycol, &ypl[buf][0][0]);
    if (w < 2) load_lds16(gBC + (size_t)(l0 + crow) * 32 + ccol, &Cl[buf][(w & 1) * 16][0]);
    else       load_lds16(gg + (size_t)(l0 + grow) * 4096 + gcol, &gl2[buf][(w & 1) * 16][0]);
  };

  stage(0, 0);
  float cum = 0.f;
  const int nch = SEG_T / SCAN_T;  // 8
  for (int c = 0; c < nch; ++c) {
    int cur = c & 1;
    if (c + 1 < nch) {
      stage(cur ^ 1, c + 1);
      if (nloads == 2) { asm volatile("s_waitcnt vmcnt(2)" ::: "memory"); }
      else             { asm volatile("s_waitcnt vmcnt(1)" ::: "memory"); }
    } else {
      asm volatile("s_waitcnt vmcnt(0)" ::: "memory");
    }
    __syncthreads();
    const unsigned short (*dc_)[16] = dl[cur];
    const float (*Cc_)[16] = Cl[cur];
#pragma unroll 8
    for (int t = 0; t < SCAN_T; ++t) {
      float dcv = bf2f(dc_[t][el]);
      cum += dcv;
      float a = A2 * cum, pw;
      asm("v_exp_f32 %0, %1" : "=v"(pw) : "v"(a));
      float p = (pw * h) * Cc_[t][n];
      p += dpp_mov<0xB1>(p);
      p += dpp_mov<0x4E>(p);
      p += dpp_mov<0x141>(p);
      if ((n & 7) == 0) ycl[t][el][n >> 3] = p;
    }
    __syncthreads();
    {
      int t = tid >> 3, part = tid & 7;
      int l0 = seg * SEG_T + c * SCAN_T;
      ushort2_t o;
#pragma unroll
      for (int j = 0; j < 2; ++j) {
        int ee = part * 2 + j;
        float y = ycl[t][ee][0] + ycl[t][ee][1] + bf2f(ypl[cur][t][ee]);
        o[j] = f2bf(y * gl2[cur][t][ee]);
      }
      *(ushort2_t*)(gy + (size_t)(l0 + t) * NE + part * 2) = o;
    }
    __syncthreads();
  }
}

// ---------------- host launcher ----------------
extern "C" void kernel_launch(void* const* d_in, const int* in_sizes, int n_in,
                              void* d_out, int out_size, void* d_ws, size_t ws_size,
                              hipStream_t stream) {
  const float* resid  = (const float*)d_in[0];
  const float* norm_w = (const float*)d_in[1];
  const float* skip_w = (const float*)d_in[2];
  const float* in_w   = (const float*)d_in[3];
  const float* conv_w = (const float*)d_in[4];
  const float* conv_b = (const float*)d_in[5];
  const float* wd1    = (const float*)d_in[6];
  const float* wd2    = (const float*)d_in[7];
  const float* wd2_b  = (const float*)d_in[8];
  const float* wB     = (const float*)d_in[9];
  const float* wC     = (const float*)d_in[10];
  const float* A_log  = (const float*)d_in[11];
  const float* W_D    = (const float*)d_in[12];
  const float* out_w  = (const float*)d_in[13];
  float* out = (float*)d_out;

  char* ws = (char*)d_ws;
  size_t off = 0;
  auto alloc = [&](size_t bytes) -> void* {
    void* p = ws + off;
    off += (bytes + 255) & ~(size_t)255;
    return p;
  };
  unsigned short* rn_bf      = (unsigned short*)alloc((size_t)NBL * ND * 2);
  unsigned short* wskipin_bf = (unsigned short*)alloc((size_t)2 * NE * ND * 2);  // [skip_w; in_w]
  unsigned short* wout_bf    = (unsigned short*)alloc((size_t)ND * NE * 2);
  unsigned short* wd2_bf     = (unsigned short*)alloc((size_t)NE * NR * 2);
  unsigned short* wcat_bf    = (unsigned short*)alloc((size_t)256 * NE * 2);
  float* g_f                 = (float*)alloc((size_t)NBL * NE * 4);   // silu(skip)  33.55MB
  unsigned short* xin_bf     = (unsigned short*)alloc((size_t)NBL * NE * 2);  // 16.78MB
  unsigned short* x_bf       = (unsigned short*)alloc((size_t)NBL * NE * 2);  // 16.78MB
  float* part_f              = (float*)alloc((size_t)16 * NBL * 256 * 4);
  unsigned short* t_bf       = (unsigned short*)alloc((size_t)NBL * NR * 2);
  float* bc_f                = (float*)alloc((size_t)NBL * 32 * 4);
  unsigned short* yg_bf      = (unsigned short*)alloc((size_t)NBL * NE * 2);
  float* fin_f               = (float*)alloc((size_t)4 * NB * NE * 16 * 4);
  float* dtot_f              = (float*)alloc((size_t)4 * NB * NE * 4);
  // delta (bf16) aliases wskipin_bf (consumed by step 3, rewritten each replay).
  unsigned short* delta_bf = wskipin_bf;
  // out-GEMM split-K partials (4 x 16.78MB = 67.1MB) alias g_f+xin_bf+x_bf
  // (exactly 67.1MB contiguous, all dead after scan2 -> stream-ordered safe).
  float* part2_f = g_f;
  (void)ws_size; (void)in_sizes; (void)n_in; (void)out_size;

  // 1. RMSNorm -> rn bf16
  rmsnorm_kernel<<<dim3(NBL), dim3(256), 0, stream>>>(resid, norm_w, rn_bf);

  // 2. weight casts
  cast_bf16_kernel<<<dim3((NE * ND / 8 + 255) / 256), dim3(256), 0, stream>>>(skip_w, wskipin_bf, NE * ND / 8);
  cast_bf16_kernel<<<dim3((NE * ND / 8 + 255) / 256), dim3(256), 0, stream>>>(in_w, wskipin_bf + (size_t)NE * ND, NE * ND / 8);
  cast_bf16_kernel<<<dim3((ND * NE / 8 + 255) / 256), dim3(256), 0, stream>>>(out_w, wout_bf, ND * NE / 8);
  cast_bf16_kernel<<<dim3((NE * NR / 8 + 255) / 256), dim3(256), 0, stream>>>(wd2, wd2_bf, NE * NR / 8);
  build_wcat_kernel<<<dim3(256 * NE / 8 / 256), dim3(256), 0, stream>>>(wd1, wB, wC, wcat_bf);

  // 3. fused [g|xin] = rn @ [skip_w; in_w]^T  (2-buffer ring, 2 blocks/CU)
  gemm256_fused<<<dim3(8192 / 256, NBL / 256), dim3(512), 0, stream>>>(
      rn_bf, wskipin_bf, g_f, xin_bf);

  // 5. conv + silu -> x_bf
  conv_silu_kernel<<<dim3((int)(((size_t)NB * NL * NE) / 256)), dim3(256), 0, stream>>>(
      xin_bf, conv_w, conv_b, x_bf);

  // 6. tcat = x @ [wd1;wB;wC]^T  split-K=16 -> partials
  gemm_bt<0><<<dim3(256 / 128, NBL / 128, 16), dim3(256), 0, stream>>>(
      x_bf, wcat_bf, part_f, NBL, 256, NE, (NE / 32) / 16, nullptr, nullptr);
  // 7. reduce partials -> t_bf, bc (interleaved B|C)
  reduce_tcat_kernel<<<dim3((NBL * 160 + 255) / 256), dim3(256), 0, stream>>>(
      part_f, t_bf, bc_f);

  // 8. delta = softplus(t @ wd2^T + wd2_b) -> bf16  [2048,4096] k=128
  gemm_bt<1><<<dim3(NE / 128, NBL / 128, 1), dim3(256), 0, stream>>>(
      t_bf, wd2_bf, (float*)delta_bf, NBL, NE, NR, NR / 32, wd2_b, nullptr);

  // 9a. segment-local scans (4-way L-split)
  scan1_kernel<<<dim3(NE / 16, NB * 4), dim3(256), 0, stream>>>(
      delta_bf, x_bf, bc_f, g_f, A_log, W_D, yg_bf, fin_f, dtot_f);
  // 9b. fixup segments 1..3 (+ gating)
  scan2_kernel<<<dim3(NE / 16, NB * 3), dim3(256), 0, stream>>>(
      delta_bf, yg_bf, bc_f, g_f, A_log, fin_f, dtot_f);

  // 10a. out partials = yg @ out_w^T  split-K=4  [2048,2048] k=1024 each
  gemm_bt<0><<<dim3(ND / 128, NBL / 128, 4), dim3(256), 0, stream>>>(
      yg_bf, wout_bf, part2_f, NBL, ND, NE, (NE / 32) / 4, nullptr, nullptr);
  // 10b. out = resid + sum partials
  reduce_out_kernel<<<dim3((int)((size_t)NBL * ND / 4 / 256)), dim3(256), 0, stream>>>(
      part2_f, resid, out);
}

// Round 18
// 407.249 us; speedup vs baseline: 2.1141x; 2.1141x over previous
//
#include <hip/hip_runtime.h>
#include <stdint.h>

// ---- problem constants ----
#define NB 2
#define NL 1024
#define ND 2048
#define NE 4096
#define NN 16
#define NR 128
#define NKC 4
#define NBL (NB*NL)          // 2048 rows
#define EPSV 1e-5f
#define SEG_T 256            // scan L-split segment length (4 segments)
#define SCAN_T 32            // LDS chunk within a segment (small -> high occupancy)

typedef __attribute__((ext_vector_type(4))) float f32x4;
typedef __attribute__((ext_vector_type(8))) short short8;
typedef __attribute__((ext_vector_type(8))) unsigned short ushort8;
typedef __attribute__((ext_vector_type(4))) unsigned short ushort4_t;
typedef __attribute__((ext_vector_type(2))) unsigned short ushort2_t;

__device__ __forceinline__ unsigned short f2bf(float f) {
  union { float f; unsigned u; } v; v.f = f;
  unsigned r = v.u + 0x7FFFu + ((v.u >> 16) & 1u);   // RNE
  return (unsigned short)(r >> 16);
}

__device__ __forceinline__ float bf2f(unsigned short u) {
  union { unsigned u; float f; } v; v.u = (unsigned)u << 16; return v.f;
}

__device__ __forceinline__ void load_lds16(const void* g, void* l) {
  __builtin_amdgcn_global_load_lds((const __attribute__((address_space(1))) void*)g,
                                   (__attribute__((address_space(3))) void*)l,
                                   16, 0, 0);
}

// LDS swizzle for gemm_bt tiles (measured neutral in r13 — kept, harmless).
__device__ __forceinline__ int swzmask(int row) {  // element-offset mask (x8)
  return ((row ^ (row >> 2)) & 3) * 8;
}

template<int CTRL>
__device__ __forceinline__ float dpp_mov(float v) {
  return __int_as_float(__builtin_amdgcn_update_dpp(
      0, __float_as_int(v), CTRL, 0xF, 0xF, true));
}

// ---------------- RMSNorm: resid[row,0:2048] -> rn_bf16 ----------------
__global__ void rmsnorm_kernel(const float* __restrict__ resid,
                               const float* __restrict__ nw,
                               unsigned short* __restrict__ rn) {
  int row = blockIdx.x;
  int tid = threadIdx.x;                 // 256 threads, 8 f32 each
  const float* r = resid + (size_t)row * ND;
  f32x4 v0 = *(const f32x4*)(r + tid * 8);
  f32x4 v1 = *(const f32x4*)(r + tid * 8 + 4);
  float vals[8];
#pragma unroll
  for (int i = 0; i < 4; ++i) { vals[i] = v0[i]; vals[4 + i] = v1[i]; }
  float ss = 0.f;
#pragma unroll
  for (int i = 0; i < 8; ++i) ss += vals[i] * vals[i];
  for (int o = 32; o > 0; o >>= 1) ss += __shfl_down(ss, o);
  __shared__ float ps[4];
  if ((tid & 63) == 0) ps[tid >> 6] = ss;
  __syncthreads();
  float tot = ps[0] + ps[1] + ps[2] + ps[3];
  float scale = rsqrtf(tot / (float)ND + EPSV);
  ushort8 o8;
#pragma unroll
  for (int i = 0; i < 8; ++i) o8[i] = f2bf(vals[i] * scale * nw[tid * 8 + i]);
  *(ushort8*)(rn + (size_t)row * ND + tid * 8) = o8;
}

// ---------------- generic f32 -> bf16 cast (8 elems/thread) ----------------
__global__ void cast_bf16_kernel(const float* __restrict__ in,
                                 unsigned short* __restrict__ out, int n8) {
  int i = blockIdx.x * blockDim.x + threadIdx.x;
  if (i >= n8) return;
  f32x4 a = *(const f32x4*)(in + (size_t)i * 8);
  f32x4 b = *(const f32x4*)(in + (size_t)i * 8 + 4);
  ushort8 o;
#pragma unroll
  for (int j = 0; j < 4; ++j) { o[j] = f2bf(a[j]); o[4 + j] = f2bf(b[j]); }
  *(ushort8*)(out + (size_t)i * 8) = o;
}

// ---- build concatenated [256 x 4096] bf16 weight: rows 0-127 wd1, 128-143 wB, 144-159 wC, rest 0
__global__ void build_wcat_kernel(const float* __restrict__ wd1,
                                  const float* __restrict__ wB,
                                  const float* __restrict__ wC,
                                  unsigned short* __restrict__ out) {
  int i = blockIdx.x * blockDim.x + threadIdx.x;   // total 256*4096/8 = 131072
  if (i >= 256 * NE / 8) return;
  int col8 = i & (NE / 8 - 1);
  int row = i >> 9;
  const float* src = nullptr; int srow = 0;
  if (row < 128)      { src = wd1; srow = row; }
  else if (row < 144) { src = wB;  srow = row - 128; }
  else if (row < 160) { src = wC;  srow = row - 144; }
  ushort8 o;
  if (src) {
    f32x4 a = *(const f32x4*)(src + (size_t)srow * NE + col8 * 8);
    f32x4 b = *(const f32x4*)(src + (size_t)srow * NE + col8 * 8 + 4);
#pragma unroll
    for (int j = 0; j < 4; ++j) { o[j] = f2bf(a[j]); o[4 + j] = f2bf(b[j]); }
  } else {
#pragma unroll
    for (int j = 0; j < 8; ++j) o[j] = 0;
  }
  *(ushort8*)(out + (size_t)row * NE + col8 * 8) = o;
}

// ======== 256x256 GEMM, 3-buffer ring, single-barrier K-tile (fused skip+in) ========
// Best measured config (r16, 83.5us): XCD-locality remap + counted vmcnt(4).
// r17 lesson: 2 blocks/CU impossible (acc=128 VGPR > budget at 4 waves/SIMD ->
// spill catastrophe). This kernel is delivery-bound at ~6.4 TB/s aggregate.
__global__ __launch_bounds__(512, 2)
void gemm256_fused(const unsigned short* __restrict__ A,
                   const unsigned short* __restrict__ B,
                   float* __restrict__ Gout,
                   unsigned short* __restrict__ Xout) {
  const int K = 2048, NH = K / 32;   // 64 K-tiles
  __shared__ unsigned short Asl[3][256 * 32];   // 16KB each
  __shared__ unsigned short Bsl[3][256 * 32];
  int tid = threadIdx.x;
  int w = tid >> 6, lane = tid & 63;
  int wm = w >> 2, wn = w & 3;
  int lr = lane & 15, kg8 = (lane >> 4) * 8;
  // XCD remap: linear dispatch id L; HW xcd = L%8 (round-robin heuristic).
  // XCD k owns n-tiles [4k,4k+4) x m-tiles [0,8). Bijective (256 blocks).
  int L = blockIdx.x + gridDim.x * blockIdx.y;
  int xcd = L & 7, p = L >> 3;
  int m0 = (p >> 2) * 256;
  int n0 = (xcd * 4 + (p & 3)) * 256;

  // staging: thread covers row tid>>2, 16B-col tid&3 of a 128x32 half-tile.
  int srow = tid >> 2, scol = (tid & 3) * 8;
  const unsigned short* ga = A + (size_t)(m0 + srow) * K + scol;
  const unsigned short* gb = B + (size_t)(n0 + srow) * K + scol;

  // half j: 0=A rows 0-127, 1=A rows 128-255, 2=B rows 0-127, 3=B rows 128-255.
  auto stageHalf = [&](int bufS, int t, int j) {
    int k0 = t * 32;
    if (j < 2)
      load_lds16(ga + (size_t)j * 128 * K + k0,
                 (char*)&Asl[bufS][0] + j * 8192 + w * 1024);
    else
      load_lds16(gb + (size_t)(j - 2) * 128 * K + k0,
                 (char*)&Bsl[bufS][0] + (j - 2) * 8192 + w * 1024);
  };

  f32x4 acc[8][4];
#pragma unroll
  for (int i = 0; i < 8; ++i)
#pragma unroll
    for (int j = 0; j < 4; ++j) acc[i][j] = (f32x4){0.f, 0.f, 0.f, 0.f};

  // prologue: K-tiles 0 and 1 fully staged (8 loads/wave in flight)
#pragma unroll
  for (int j = 0; j < 4; ++j) stageHalf(0, 0, j);
#pragma unroll
  for (int j = 0; j < 4; ++j) stageHalf(1, 1, j);

  int buf = 0, bufS = 2;
  int arow = wm * 128 + lr;
  int brow = wn * 64 + lr;

  for (int t = 0; t < NH; ++t) {
    if (t + 1 < NH) { asm volatile("s_waitcnt vmcnt(4)" ::: "memory"); }
    else            { asm volatile("s_waitcnt vmcnt(0)" ::: "memory"); }
    __builtin_amdgcn_s_barrier();
    const unsigned short* As_ = &Asl[buf][0];
    const unsigned short* Bs_ = &Bsl[buf][0];
    bool st = (t + 2 < NH);
    short8 a[8], b[4];
    // ---- quadrant m0 x n0 ----
#pragma unroll
    for (int i = 0; i < 4; ++i)
      a[i] = *(const short8*)&As_[(arow + i * 16) * 32 + kg8];
#pragma unroll
    for (int j = 0; j < 2; ++j)
      b[j] = *(const short8*)&Bs_[(brow + j * 16) * 32 + kg8];
    if (st) stageHalf(bufS, t + 2, 0);
    __builtin_amdgcn_s_setprio(1);
#pragma unroll
    for (int i = 0; i < 4; ++i)
#pragma unroll
      for (int j = 0; j < 2; ++j)
        acc[i][j] = __builtin_amdgcn_mfma_f32_16x16x32_bf16(a[i], b[j], acc[i][j], 0, 0, 0);
    __builtin_amdgcn_s_setprio(0);
    // ---- quadrant m0 x n1 ----
#pragma unroll
    for (int j = 2; j < 4; ++j)
      b[j] = *(const short8*)&Bs_[(brow + j * 16) * 32 + kg8];
    if (st) stageHalf(bufS, t + 2, 1);
    __builtin_amdgcn_s_setprio(1);
#pragma unroll
    for (int i = 0; i < 4; ++i)
#pragma unroll
      for (int j = 2; j < 4; ++j)
        acc[i][j] = __builtin_amdgcn_mfma_f32_16x16x32_bf16(a[i], b[j], acc[i][j], 0, 0, 0);
    __builtin_amdgcn_s_setprio(0);
    // ---- quadrant m1 x n1 ----
#pragma unroll
    for (int i = 4; i < 8; ++i)
      a[i] = *(const short8*)&As_[(arow + i * 16) * 32 + kg8];
    if (st) stageHalf(bufS, t + 2, 2);
    __builtin_amdgcn_s_setprio(1);
#pragma unroll
    for (int i = 4; i < 8; ++i)
#pragma unroll
      for (int j = 2; j < 4; ++j)
        acc[i][j] = __builtin_amdgcn_mfma_f32_16x16x32_bf16(a[i], b[j], acc[i][j], 0, 0, 0);
    __builtin_amdgcn_s_setprio(0);
    // ---- quadrant m1 x n0 (b[0],b[1] still live) ----
    if (st) stageHalf(bufS, t + 2, 3);
    __builtin_amdgcn_s_setprio(1);
#pragma unroll
    for (int i = 4; i < 8; ++i)
#pragma unroll
      for (int j = 0; j < 2; ++j)
        acc[i][j] = __builtin_amdgcn_mfma_f32_16x16x32_bf16(a[i], b[j], acc[i][j], 0, 0, 0);
    __builtin_amdgcn_s_setprio(0);
    buf  = (buf  == 2) ? 0 : buf  + 1;
    bufS = (bufS == 2) ? 0 : bufS + 1;
  }

  // epilogue: C/D col=lane&15, row=(lane>>4)*4+reg (verified layout)
  int rbase = m0 + wm * 128 + (lane >> 4) * 4;
  int cbase = n0 + wn * 64 + (lane & 15);
  bool isg = (n0 < 4096);
#pragma unroll
  for (int mf = 0; mf < 8; ++mf) {
#pragma unroll
    for (int nf = 0; nf < 4; ++nf) {
      int col = cbase + nf * 16;
#pragma unroll
      for (int rr = 0; rr < 4; ++rr) {
        int row = rbase + mf * 16 + rr;
        float v = acc[mf][nf][rr];
        if (isg) Gout[(size_t)row * 4096 + col] = v / (1.f + __expf(-v));
        else     Xout[(size_t)row * 4096 + (col - 4096)] = f2bf(v);
      }
    }
  }
}

// ---------------- bf16 MFMA GEMM, 3-slot ring pipeline (T3+T4+T5) ----------------
// MODE 0: f32 partials (split-K via z); MODE 1: softplus->bf16.
template<int MODE>
__global__ __launch_bounds__(256)
void gemm_bt(const unsigned short* __restrict__ A,
             const unsigned short* __restrict__ B,
             float* __restrict__ C,
             int M, int N, int K, int ksteps_per_z,
             const float* __restrict__ bias,
             unsigned short* __restrict__ out2) {
  __shared__ unsigned short As[3][128 * 32];
  __shared__ unsigned short Bs[3][128 * 32];
  int tid = threadIdx.x;
  int w = tid >> 6, lane = tid & 63;
  int m0 = blockIdx.y * 128, n0 = blockIdx.x * 128;
  int kz0 = blockIdx.z * ksteps_per_z * 32;
  if (MODE == 0) C += (size_t)blockIdx.z * M * N;
  const int NH = ksteps_per_z;

  f32x4 acc[4][4];
#pragma unroll
  for (int i = 0; i < 4; ++i)
#pragma unroll
    for (int j = 0; j < 4; ++j) acc[i][j] = (f32x4){0.f, 0.f, 0.f, 0.f};

  int wm = w >> 1, wn = w & 1;
  int lr = lane & 15, kg = lane >> 4;

  int fe0 = (w) * 512 + lane * 8;
  int fe1 = (4 + w) * 512 + lane * 8;
  int r0 = fe0 >> 5, c0 = fe0 & 31;
  int r1 = fe1 >> 5, c1 = fe1 & 31;
  int sc0 = c0 ^ swzmask(r0);
  int sc1 = c1 ^ swzmask(r1);
  const unsigned short* Ag0 = A + (size_t)(m0 + r0) * K + sc0 + kz0;
  const unsigned short* Ag1 = A + (size_t)(m0 + r1) * K + sc1 + kz0;
  const unsigned short* Bg0 = B + (size_t)(n0 + r0) * K + sc0 + kz0;
  const unsigned short* Bg1 = B + (size_t)(n0 + r1) * K + sc1 + kz0;

  auto stage = [&](int h) {
    int slot = h % 3, kk = h * 32;
    load_lds16(Ag0 + kk, &As[slot][(w) * 512]);
    load_lds16(Ag1 + kk, &As[slot][(4 + w) * 512]);
    load_lds16(Bg0 + kk, &Bs[slot][(w) * 512]);
    load_lds16(Bg1 + kk, &Bs[slot][(4 + w) * 512]);
  };

  stage(0);
  if (NH > 1) stage(1);

  int kgs = (kg * 8) ^ swzmask(lr);

  for (int h = 0; h < NH; ++h) {
    int slot = h % 3;
    __builtin_amdgcn_s_barrier();
    if (h + 2 < NH) stage(h + 2);
    int rem = NH - 1 - h;
    if (rem >= 2)      { asm volatile("s_waitcnt vmcnt(8)" ::: "memory"); }
    else if (rem == 1) { asm volatile("s_waitcnt vmcnt(4)" ::: "memory"); }
    else               { asm volatile("s_waitcnt vmcnt(0)" ::: "memory"); }
    __builtin_amdgcn_s_barrier();
    short8 a[4], b[4];
#pragma unroll
    for (int i = 0; i < 4; ++i)
      a[i] = *(const short8*)&As[slot][(wm * 64 + i * 16 + lr) * 32 + kgs];
#pragma unroll
    for (int j = 0; j < 4; ++j)
      b[j] = *(const short8*)&Bs[slot][(wn * 64 + j * 16 + lr) * 32 + kgs];
    __builtin_amdgcn_s_setprio(1);
#pragma unroll
    for (int i = 0; i < 4; ++i)
#pragma unroll
      for (int j = 0; j < 4; ++j)
        acc[i][j] = __builtin_amdgcn_mfma_f32_16x16x32_bf16(a[i], b[j], acc[i][j], 0, 0, 0);
    __builtin_amdgcn_s_setprio(0);
  }

#pragma unroll
  for (int i = 0; i < 4; ++i) {
#pragma unroll
    for (int j = 0; j < 4; ++j) {
      int rbase = m0 + wm * 64 + i * 16 + kg * 4;
      int col = n0 + wn * 64 + j * 16 + lr;
#pragma unroll
      for (int r = 0; r < 4; ++r) {
        float v = acc[i][j][r];
        if (MODE == 0) {
          C[(size_t)(rbase + r) * N + col] = v;
        } else {
          float t = v + bias[col];
          ((unsigned short*)C)[(size_t)(rbase + r) * N + col] =
              f2bf((t > 20.f) ? t : log1pf(__expf(t)));
        }
      }
    }
  }
  (void)out2;
}

// ---------------- out reduction: out = resid + sum_z part[z] ----------------
__global__ void reduce_out_kernel(const float* __restrict__ part,
                                  const float* __restrict__ resid,
                                  float* __restrict__ out) {
  size_t base = ((size_t)blockIdx.x * blockDim.x + threadIdx.x) * 4;
  if (base >= (size_t)NBL * ND) return;
  f32x4 r = *(const f32x4*)(resid + base);
#pragma unroll
  for (int z = 0; z < 4; ++z)
    r += *(const f32x4*)(part + (size_t)z * NBL * ND + base);
  *(f32x4*)(out + base) = r;
}

// ---------------- depthwise causal conv (K=4) + SiLU -> bf16 ----------------
__global__ void conv_silu_kernel(const unsigned short* __restrict__ xin,
                                 const float* __restrict__ cw,
                                 const float* __restrict__ cb,
                                 unsigned short* __restrict__ xbf) {
  size_t idx = (size_t)blockIdx.x * blockDim.x + threadIdx.x;
  if (idx >= (size_t)NB * NL * NE) return;
  int e = (int)(idx & (NE - 1));
  int r = (int)(idx >> 12);            // b*NL + l
  int l = r & (NL - 1);
  float acc = cb[e];
#pragma unroll
  for (int k = 0; k < NKC; ++k) {
    int ls = l - 3 + k;
    if (ls >= 0) acc += bf2f(xin[(size_t)(r - 3 + k) * NE + e]) * cw[e * 4 + k];
  }
  float s = acc / (1.f + __expf(-acc));
  xbf[idx] = f2bf(s);
}

// ---------------- reduce split-K partials of the concat GEMM (16 slices) ----------------
__global__ void reduce_tcat_kernel(const float* __restrict__ part,
                                   unsigned short* __restrict__ tbf,
                                   float* __restrict__ bc) {
  int idx = blockIdx.x * blockDim.x + threadIdx.x;
  if (idx >= NBL * 160) return;
  int m = idx / 160, c = idx - m * 160;
  float s = 0.f;
#pragma unroll
  for (int z = 0; z < 16; ++z) s += part[(size_t)z * NBL * 256 + (size_t)m * 256 + c];
  if (c < 128) tbf[m * 128 + c] = f2bf(s);
  else if (c < 144) bc[m * 32 + (c - 128)] = s;
  else bc[m * 32 + 16 + (c - 144)] = s;
}

// ======== selective scan, 4-way L-split, SCAN_T=32 (high occupancy) ========
__global__ __launch_bounds__(256)
void scan1_kernel(const unsigned short* __restrict__ delta_bf,
                  const unsigned short* __restrict__ x_bf,
                  const float* __restrict__ bc,
                  const float* __restrict__ gf,
                  const float* __restrict__ A_log,
                  const float* __restrict__ W_D,
                  unsigned short* __restrict__ yg,
                  float* __restrict__ fin,
                  float* __restrict__ dtot) {
  __shared__ unsigned short dxl[2][SCAN_T][2][16];  // [buf][t][{d,x}][e]  4KB
  __shared__ float gl[2][SCAN_T][16];               // 4KB
  __shared__ float BCl[2][SCAN_T][32];              // 8KB
  __shared__ float yl2[SCAN_T][16][2];              // 4KB
  __shared__ float wdl[16];
  int tid = threadIdx.x;
  int n = tid & 15, el = tid >> 4;
  int w = tid >> 6, lane = tid & 63;
  int e0 = blockIdx.x * 16;
  int b = blockIdx.y >> 2, seg = blockIdx.y & 3;
  int e = e0 + el;
  float A2 = -__expf(A_log[e * 16 + n]) * 1.44269504f;
  if (tid < 16) wdl[tid] = W_D[e0 + tid];
  float h = 0.f, cum = 0.f;

  const unsigned short* gdl = delta_bf + (size_t)b * NL * NE + e0;
  const unsigned short* gx  = x_bf + (size_t)b * NL * NE + e0;
  const float* gg  = gf + (size_t)b * NL * 4096 + e0;
  const float* gBC = bc + (size_t)b * NL * 32;

  const unsigned short* dxsrc = ((lane >> 1) & 1) ? gx : gdl;  // waves 0,1
  int dxrow = (w & 1) * 16 + (lane >> 2);
  int dxcol = (lane & 1) * 8;
  int grow = (w & 1) * 16 + (lane >> 2);                        // waves 2,3
  int gcol = (lane & 3) * 4;
  int bcrow = w * 8 + (lane >> 3);                              // all waves
  int bccol = (lane & 7) * 4;
  int nloads = (seg == 0 || w < 2) ? 2 : 1;

  auto stage = [&](int buf, int c) {
    int l0 = seg * SEG_T + c * SCAN_T;
    if (w < 2)
      load_lds16(dxsrc + (size_t)(l0 + dxrow) * NE + dxcol, &dxl[buf][(w & 1) * 16][0][0]);
    else if (seg == 0)
      load_lds16(gg + (size_t)(l0 + grow) * 4096 + gcol, &gl[buf][(w & 1) * 16][0]);
    load_lds16(gBC + (size_t)(l0 + bcrow) * 32 + bccol, &BCl[buf][w * 8][0]);
  };

  stage(0, 0);
  const int nch = SEG_T / SCAN_T;  // 8
  for (int c = 0; c < nch; ++c) {
    int cur = c & 1;
    if (c + 1 < nch) {
      stage(cur ^ 1, c + 1);
      if (nloads == 2) { asm volatile("s_waitcnt vmcnt(2)" ::: "memory"); }
      else             { asm volatile("s_waitcnt vmcnt(1)" ::: "memory"); }
    } else {
      asm volatile("s_waitcnt vmcnt(0)" ::: "memory");
    }
    __syncthreads();
    const unsigned short (*dxc)[2][16] = dxl[cur];
    const float (*BCc)[32] = BCl[cur];
#pragma unroll 8
    for (int t = 0; t < SCAN_T; ++t) {
      float dc = bf2f(dxc[t][0][el]);
      float xc = bf2f(dxc[t][1][el]);
      float Bc = BCc[t][n];
      float Cc = BCc[t][16 + n];
      cum += dc;
      float a = dc * A2, ed;
      asm("v_exp_f32 %0, %1" : "=v"(ed) : "v"(a));   // exp2(d*A*log2e)
      h = ed * h + (dc * xc) * Bc;
      float p = h * Cc;
      p += dpp_mov<0xB1>(p);    // xor1
      p += dpp_mov<0x4E>(p);    // xor2
      p += dpp_mov<0x141>(p);   // half-mirror -> lanes 0,8 hold 8-group sums
      if ((n & 7) == 0) yl2[t][el][n >> 3] = p;
    }
    __syncthreads();
    {
      int t = tid >> 3, part = tid & 7;   // 2 e's per thread
      int l0 = seg * SEG_T + c * SCAN_T;
      ushort2_t o;
#pragma unroll
      for (int j = 0; j < 2; ++j) {
        int ee = part * 2 + j;
        float xv = bf2f(dxc[t][1][ee]);
        float y = yl2[t][ee][0] + yl2[t][ee][1] + xv * wdl[ee];
        if (seg == 0) y *= gl[cur][t][ee];
        o[j] = f2bf(y);
      }
      *(ushort2_t*)(yg + (size_t)(b * NL + l0 + t) * NE + e0 + part * 2) = o;
    }
    __syncthreads();
  }
  fin[(size_t)((seg * 2 + b) * 4096 + e) * 16 + n] = h;
  if (n == 0) dtot[(size_t)(seg * 2 + b) * 4096 + e] = cum;
}

// K2: fixup for segments 1..3
__global__ __launch_bounds__(256)
void scan2_kernel(const unsigned short* __restrict__ delta_bf,
                  unsigned short* __restrict__ yg,
                  const float* __restrict__ bc,
                  const float* __restrict__ gf,
                  const float* __restrict__ A_log,
                  const float* __restrict__ fin,
                  const float* __restrict__ dtot) {
  __shared__ unsigned short dl[2][SCAN_T][16];      // 2KB
  __shared__ unsigned short ypl[2][SCAN_T][16];     // 2KB
  __shared__ float Cl[2][SCAN_T][16];               // 4KB
  __shared__ float gl2[2][SCAN_T][16];              // 4KB
  __shared__ float ycl[SCAN_T][16][2];              // 4KB
  int tid = threadIdx.x;
  int n = tid & 15, el = tid >> 4;
  int w = tid >> 6, lane = tid & 63;
  int e0 = blockIdx.x * 16;
  int b = blockIdx.y / 3, seg = 1 + blockIdx.y % 3;
  int e = e0 + el;
  float A2 = -__expf(A_log[e * 16 + n]) * 1.44269504f;
  float h = fin[(size_t)(b * 4096 + e) * 16 + n];           // seg 0 final
  for (int s2 = 1; s2 < seg; ++s2) {
    float dt = dtot[(size_t)(s2 * 2 + b) * 4096 + e];
    float a = A2 * dt, pw;
    asm("v_exp_f32 %0, %1" : "=v"(pw) : "v"(a));
    h = fin[(size_t)((s2 * 2 + b) * 4096 + e) * 16 + n] + pw * h;
  }

  const unsigned short* gd = delta_bf + (size_t)b * NL * NE + e0;
  unsigned short* gy = yg + (size_t)b * NL * NE + e0;
  const float* gg  = gf + (size_t)b * NL * 4096 + e0;
  const float* gBC = bc + (size_t)b * NL * 32;

  int dyrow = lane >> 1;
  int dycol = (lane & 1) * 8;
  int crow = (w & 1) * 16 + (lane >> 2);
  int ccol = 16 + (lane & 3) * 4;
  int grow = (w & 1) * 16 + (lane >> 2);
  int gcol = (lane & 3) * 4;
  int nloads = (w < 2) ? 2 : 1;

  auto stage = [&](int buf, int c) {
    int l0 = seg * SEG_T + c * SCAN_T;
    if (w == 0)      load_lds16(gd + (size_t)(l0 + dyrow) * NE + dycol, &dl[buf][0][0]);
    else if (w == 1) load_lds16(gy + (size_t)(l0 + dyrow) * NE + dycol, &ypl[buf][0][0]);
    if (w < 2) load_lds16(gBC + (size_t)(l0 + crow) * 32 + ccol, &Cl[buf][(w & 1) * 16][0]);
    else       load_lds16(gg + (size_t)(l0 + grow) * 4096 + gcol, &gl2[buf][(w & 1) * 16][0]);
  };

  stage(0, 0);
  float cum = 0.f;
  const int nch = SEG_T / SCAN_T;  // 8
  for (int c = 0; c < nch; ++c) {
    int cur = c & 1;
    if (c + 1 < nch) {
      stage(cur ^ 1, c + 1);
      if (nloads == 2) { asm volatile("s_waitcnt vmcnt(2)" ::: "memory"); }
      else             { asm volatile("s_waitcnt vmcnt(1)" ::: "memory"); }
    } else {
      asm volatile("s_waitcnt vmcnt(0)" ::: "memory");
    }
    __syncthreads();
    const unsigned short (*dc_)[16] = dl[cur];
    const float (*Cc_)[16] = Cl[cur];
#pragma unroll 8
    for (int t = 0; t < SCAN_T; ++t) {
      float dcv = bf2f(dc_[t][el]);
      cum += dcv;
      float a = A2 * cum, pw;
      asm("v_exp_f32 %0, %1" : "=v"(pw) : "v"(a));
      float p = (pw * h) * Cc_[t][n];
      p += dpp_mov<0xB1>(p);
      p += dpp_mov<0x4E>(p);
      p += dpp_mov<0x141>(p);
      if ((n & 7) == 0) ycl[t][el][n >> 3] = p;
    }
    __syncthreads();
    {
      int t = tid >> 3, part = tid & 7;
      int l0 = seg * SEG_T + c * SCAN_T;
      ushort2_t o;
#pragma unroll
      for (int j = 0; j < 2; ++j) {
        int ee = part * 2 + j;
        float y = ycl[t][ee][0] + ycl[t][ee][1] + bf2f(ypl[cur][t][ee]);
        o[j] = f2bf(y * gl2[cur][t][ee]);
      }
      *(ushort2_t*)(gy + (size_t)(l0 + t) * NE + part * 2) = o;
    }
    __syncthreads();
  }
}

// ---------------- host launcher ----------------
extern "C" void kernel_launch(void* const* d_in, const int* in_sizes, int n_in,
                              void* d_out, int out_size, void* d_ws, size_t ws_size,
                              hipStream_t stream) {
  const float* resid  = (const float*)d_in[0];
  const float* norm_w = (const float*)d_in[1];
  const float* skip_w = (const float*)d_in[2];
  const float* in_w   = (const float*)d_in[3];
  const float* conv_w = (const float*)d_in[4];
  const float* conv_b = (const float*)d_in[5];
  const float* wd1    = (const float*)d_in[6];
  const float* wd2    = (const float*)d_in[7];
  const float* wd2_b  = (const float*)d_in[8];
  const float* wB     = (const float*)d_in[9];
  const float* wC     = (const float*)d_in[10];
  const float* A_log  = (const float*)d_in[11];
  const float* W_D    = (const float*)d_in[12];
  const float* out_w  = (const float*)d_in[13];
  float* out = (float*)d_out;

  char* ws = (char*)d_ws;
  size_t off = 0;
  auto alloc = [&](size_t bytes) -> void* {
    void* p = ws + off;
    off += (bytes + 255) & ~(size_t)255;
    return p;
  };
  unsigned short* rn_bf      = (unsigned short*)alloc((size_t)NBL * ND * 2);
  unsigned short* wskipin_bf = (unsigned short*)alloc((size_t)2 * NE * ND * 2);  // [skip_w; in_w]
  unsigned short* wout_bf    = (unsigned short*)alloc((size_t)ND * NE * 2);
  unsigned short* wd2_bf     = (unsigned short*)alloc((size_t)NE * NR * 2);
  unsigned short* wcat_bf    = (unsigned short*)alloc((size_t)256 * NE * 2);
  float* g_f                 = (float*)alloc((size_t)NBL * NE * 4);   // silu(skip)  33.55MB
  unsigned short* xin_bf     = (unsigned short*)alloc((size_t)NBL * NE * 2);  // 16.78MB
  unsigned short* x_bf       = (unsigned short*)alloc((size_t)NBL * NE * 2);  // 16.78MB
  float* part_f              = (float*)alloc((size_t)16 * NBL * 256 * 4);
  unsigned short* t_bf       = (unsigned short*)alloc((size_t)NBL * NR * 2);
  float* bc_f                = (float*)alloc((size_t)NBL * 32 * 4);
  unsigned short* yg_bf      = (unsigned short*)alloc((size_t)NBL * NE * 2);
  float* fin_f               = (float*)alloc((size_t)4 * NB * NE * 16 * 4);
  float* dtot_f              = (float*)alloc((size_t)4 * NB * NE * 4);
  // delta (bf16) aliases wskipin_bf (consumed by step 3, rewritten each replay).
  unsigned short* delta_bf = wskipin_bf;
  // out-GEMM split-K partials (4 x 16.78MB = 67.1MB) alias g_f+xin_bf+x_bf
  // (exactly 67.1MB contiguous, all dead after scan2 -> stream-ordered safe).
  float* part2_f = g_f;
  (void)ws_size; (void)in_sizes; (void)n_in; (void)out_size;

  // 1. RMSNorm -> rn bf16
  rmsnorm_kernel<<<dim3(NBL), dim3(256), 0, stream>>>(resid, norm_w, rn_bf);

  // 2. weight casts
  cast_bf16_kernel<<<dim3((NE * ND / 8 + 255) / 256), dim3(256), 0, stream>>>(skip_w, wskipin_bf, NE * ND / 8);
  cast_bf16_kernel<<<dim3((NE * ND / 8 + 255) / 256), dim3(256), 0, stream>>>(in_w, wskipin_bf + (size_t)NE * ND, NE * ND / 8);
  cast_bf16_kernel<<<dim3((ND * NE / 8 + 255) / 256), dim3(256), 0, stream>>>(out_w, wout_bf, ND * NE / 8);
  cast_bf16_kernel<<<dim3((NE * NR / 8 + 255) / 256), dim3(256), 0, stream>>>(wd2, wd2_bf, NE * NR / 8);
  build_wcat_kernel<<<dim3(256 * NE / 8 / 256), dim3(256), 0, stream>>>(wd1, wB, wC, wcat_bf);

  // 3. fused [g|xin] = rn @ [skip_w; in_w]^T  (256^2 ring + XCD-locality remap)
  gemm256_fused<<<dim3(8192 / 256, NBL / 256), dim3(512), 0, stream>>>(
      rn_bf, wskipin_bf, g_f, xin_bf);

  // 5. conv + silu -> x_bf
  conv_silu_kernel<<<dim3((int)(((size_t)NB * NL * NE) / 256)), dim3(256), 0, stream>>>(
      xin_bf, conv_w, conv_b, x_bf);

  // 6. tcat = x @ [wd1;wB;wC]^T  split-K=16 -> partials
  gemm_bt<0><<<dim3(256 / 128, NBL / 128, 16), dim3(256), 0, stream>>>(
      x_bf, wcat_bf, part_f, NBL, 256, NE, (NE / 32) / 16, nullptr, nullptr);
  // 7. reduce partials -> t_bf, bc (interleaved B|C)
  reduce_tcat_kernel<<<dim3((NBL * 160 + 255) / 256), dim3(256), 0, stream>>>(
      part_f, t_bf, bc_f);

  // 8. delta = softplus(t @ wd2^T + wd2_b) -> bf16  [2048,4096] k=128
  gemm_bt<1><<<dim3(NE / 128, NBL / 128, 1), dim3(256), 0, stream>>>(
      t_bf, wd2_bf, (float*)delta_bf, NBL, NE, NR, NR / 32, wd2_b, nullptr);

  // 9a. segment-local scans (4-way L-split)
  scan1_kernel<<<dim3(NE / 16, NB * 4), dim3(256), 0, stream>>>(
      delta_bf, x_bf, bc_f, g_f, A_log, W_D, yg_bf, fin_f, dtot_f);
  // 9b. fixup segments 1..3 (+ gating)
  scan2_kernel<<<dim3(NE / 16, NB * 3), dim3(256), 0, stream>>>(
      delta_bf, yg_bf, bc_f, g_f, A_log, fin_f, dtot_f);

  // 10a. out partials = yg @ out_w^T  split-K=4  [2048,2048] k=1024 each
  gemm_bt<0><<<dim3(ND / 128, NBL / 128, 4), dim3(256), 0, stream>>>(
      yg_bf, wout_bf, part2_f, NBL, ND, NE, (NE / 32) / 4, nullptr, nullptr);
  // 10b. out = resid + sum partials
  reduce_out_kernel<<<dim3((int)((size_t)NBL * ND / 4 / 256)), dim3(256), 0, stream>>>(
      part2_f, resid, out);
}

// Round 19
// 390.878 us; speedup vs baseline: 2.2027x; 1.0419x over previous
//
#include <hip/hip_runtime.h>
#include <stdint.h>

// ---- problem constants ----
#define NB 2
#define NL 1024
#define ND 2048
#define NE 4096
#define NN 16
#define NR 128
#define NKC 4
#define NBL (NB*NL)          // 2048 rows
#define EPSV 1e-5f
#define SEG_T 256            // scan L-split segment length (4 segments)
#define SCAN_T 32            // LDS chunk within a segment (small -> high occupancy)

typedef __attribute__((ext_vector_type(4))) float f32x4;
typedef __attribute__((ext_vector_type(8))) short short8;
typedef __attribute__((ext_vector_type(8))) unsigned short ushort8;
typedef __attribute__((ext_vector_type(4))) unsigned short ushort4_t;
typedef __attribute__((ext_vector_type(2))) unsigned short ushort2_t;

__device__ __forceinline__ unsigned short f2bf(float f) {
  union { float f; unsigned u; } v; v.f = f;
  unsigned r = v.u + 0x7FFFu + ((v.u >> 16) & 1u);   // RNE
  return (unsigned short)(r >> 16);
}

__device__ __forceinline__ float bf2f(unsigned short u) {
  union { unsigned u; float f; } v; v.u = (unsigned)u << 16; return v.f;
}

__device__ __forceinline__ void load_lds16(const void* g, void* l) {
  __builtin_amdgcn_global_load_lds((const __attribute__((address_space(1))) void*)g,
                                   (__attribute__((address_space(3))) void*)l,
                                   16, 0, 0);
}

// LDS swizzle for gemm_bt tiles (measured neutral in r13 — kept, harmless).
__device__ __forceinline__ int swzmask(int row) {  // element-offset mask (x8)
  return ((row ^ (row >> 2)) & 3) * 8;
}

template<int CTRL>
__device__ __forceinline__ float dpp_mov(float v) {
  return __int_as_float(__builtin_amdgcn_update_dpp(
      0, __float_as_int(v), CTRL, 0xF, 0xF, true));
}

// ---------------- RMSNorm: resid[row,0:2048] -> rn_bf16 ----------------
__global__ void rmsnorm_kernel(const float* __restrict__ resid,
                               const float* __restrict__ nw,
                               unsigned short* __restrict__ rn) {
  int row = blockIdx.x;
  int tid = threadIdx.x;                 // 256 threads, 8 f32 each
  const float* r = resid + (size_t)row * ND;
  f32x4 v0 = *(const f32x4*)(r + tid * 8);
  f32x4 v1 = *(const f32x4*)(r + tid * 8 + 4);
  float vals[8];
#pragma unroll
  for (int i = 0; i < 4; ++i) { vals[i] = v0[i]; vals[4 + i] = v1[i]; }
  float ss = 0.f;
#pragma unroll
  for (int i = 0; i < 8; ++i) ss += vals[i] * vals[i];
  for (int o = 32; o > 0; o >>= 1) ss += __shfl_down(ss, o);
  __shared__ float ps[4];
  if ((tid & 63) == 0) ps[tid >> 6] = ss;
  __syncthreads();
  float tot = ps[0] + ps[1] + ps[2] + ps[3];
  float scale = rsqrtf(tot / (float)ND + EPSV);
  ushort8 o8;
#pragma unroll
  for (int i = 0; i < 8; ++i) o8[i] = f2bf(vals[i] * scale * nw[tid * 8 + i]);
  *(ushort8*)(rn + (size_t)row * ND + tid * 8) = o8;
}

// ---------------- generic f32 -> bf16 cast (8 elems/thread) ----------------
__global__ void cast_bf16_kernel(const float* __restrict__ in,
                                 unsigned short* __restrict__ out, int n8) {
  int i = blockIdx.x * blockDim.x + threadIdx.x;
  if (i >= n8) return;
  f32x4 a = *(const f32x4*)(in + (size_t)i * 8);
  f32x4 b = *(const f32x4*)(in + (size_t)i * 8 + 4);
  ushort8 o;
#pragma unroll
  for (int j = 0; j < 4; ++j) { o[j] = f2bf(a[j]); o[4 + j] = f2bf(b[j]); }
  *(ushort8*)(out + (size_t)i * 8) = o;
}

// ---- build concatenated [256 x 4096] bf16 weight: rows 0-127 wd1, 128-143 wB, 144-159 wC, rest 0
__global__ void build_wcat_kernel(const float* __restrict__ wd1,
                                  const float* __restrict__ wB,
                                  const float* __restrict__ wC,
                                  unsigned short* __restrict__ out) {
  int i = blockIdx.x * blockDim.x + threadIdx.x;   // total 256*4096/8 = 131072
  if (i >= 256 * NE / 8) return;
  int col8 = i & (NE / 8 - 1);
  int row = i >> 9;
  const float* src = nullptr; int srow = 0;
  if (row < 128)      { src = wd1; srow = row; }
  else if (row < 144) { src = wB;  srow = row - 128; }
  else if (row < 160) { src = wC;  srow = row - 144; }
  ushort8 o;
  if (src) {
    f32x4 a = *(const f32x4*)(src + (size_t)srow * NE + col8 * 8);
    f32x4 b = *(const f32x4*)(src + (size_t)srow * NE + col8 * 8 + 4);
#pragma unroll
    for (int j = 0; j < 4; ++j) { o[j] = f2bf(a[j]); o[4 + j] = f2bf(b[j]); }
  } else {
#pragma unroll
    for (int j = 0; j < 8; ++j) o[j] = 0;
  }
  *(ushort8*)(out + (size_t)row * NE + col8 * 8) = o;
}

// ======== 256x256 GEMM, 3-buffer ring, single-barrier K-tile (fused skip+in) ========
// Best measured config (r16/r18, ~84us): XCD-locality remap + counted vmcnt(4).
// r19: Gout stored bf16 (gate path is bf16 end-to-end; WRITE -16.8MB).
__global__ __launch_bounds__(512, 2)
void gemm256_fused(const unsigned short* __restrict__ A,
                   const unsigned short* __restrict__ B,
                   unsigned short* __restrict__ Gout,
                   unsigned short* __restrict__ Xout) {
  const int K = 2048, NH = K / 32;   // 64 K-tiles
  __shared__ unsigned short Asl[3][256 * 32];   // 16KB each
  __shared__ unsigned short Bsl[3][256 * 32];
  int tid = threadIdx.x;
  int w = tid >> 6, lane = tid & 63;
  int wm = w >> 2, wn = w & 3;
  int lr = lane & 15, kg8 = (lane >> 4) * 8;
  // XCD remap: xcd = L&7 owns 4 n-tiles x 8 m-tiles. Bijective (256 blocks).
  int L = blockIdx.x + gridDim.x * blockIdx.y;
  int xcd = L & 7, p = L >> 3;
  int m0 = (p >> 2) * 256;
  int n0 = (xcd * 4 + (p & 3)) * 256;

  // staging: thread covers row tid>>2, 16B-col tid&3 of a 128x32 half-tile.
  int srow = tid >> 2, scol = (tid & 3) * 8;
  const unsigned short* ga = A + (size_t)(m0 + srow) * K + scol;
  const unsigned short* gb = B + (size_t)(n0 + srow) * K + scol;

  // half j: 0=A rows 0-127, 1=A rows 128-255, 2=B rows 0-127, 3=B rows 128-255.
  auto stageHalf = [&](int bufS, int t, int j) {
    int k0 = t * 32;
    if (j < 2)
      load_lds16(ga + (size_t)j * 128 * K + k0,
                 (char*)&Asl[bufS][0] + j * 8192 + w * 1024);
    else
      load_lds16(gb + (size_t)(j - 2) * 128 * K + k0,
                 (char*)&Bsl[bufS][0] + (j - 2) * 8192 + w * 1024);
  };

  f32x4 acc[8][4];
#pragma unroll
  for (int i = 0; i < 8; ++i)
#pragma unroll
    for (int j = 0; j < 4; ++j) acc[i][j] = (f32x4){0.f, 0.f, 0.f, 0.f};

  // prologue: K-tiles 0 and 1 fully staged (8 loads/wave in flight)
#pragma unroll
  for (int j = 0; j < 4; ++j) stageHalf(0, 0, j);
#pragma unroll
  for (int j = 0; j < 4; ++j) stageHalf(1, 1, j);

  int buf = 0, bufS = 2;
  int arow = wm * 128 + lr;
  int brow = wn * 64 + lr;

  for (int t = 0; t < NH; ++t) {
    if (t + 1 < NH) { asm volatile("s_waitcnt vmcnt(4)" ::: "memory"); }
    else            { asm volatile("s_waitcnt vmcnt(0)" ::: "memory"); }
    __builtin_amdgcn_s_barrier();
    const unsigned short* As_ = &Asl[buf][0];
    const unsigned short* Bs_ = &Bsl[buf][0];
    bool st = (t + 2 < NH);
    short8 a[8], b[4];
    // ---- quadrant m0 x n0 ----
#pragma unroll
    for (int i = 0; i < 4; ++i)
      a[i] = *(const short8*)&As_[(arow + i * 16) * 32 + kg8];
#pragma unroll
    for (int j = 0; j < 2; ++j)
      b[j] = *(const short8*)&Bs_[(brow + j * 16) * 32 + kg8];
    if (st) stageHalf(bufS, t + 2, 0);
    __builtin_amdgcn_s_setprio(1);
#pragma unroll
    for (int i = 0; i < 4; ++i)
#pragma unroll
      for (int j = 0; j < 2; ++j)
        acc[i][j] = __builtin_amdgcn_mfma_f32_16x16x32_bf16(a[i], b[j], acc[i][j], 0, 0, 0);
    __builtin_amdgcn_s_setprio(0);
    // ---- quadrant m0 x n1 ----
#pragma unroll
    for (int j = 2; j < 4; ++j)
      b[j] = *(const short8*)&Bs_[(brow + j * 16) * 32 + kg8];
    if (st) stageHalf(bufS, t + 2, 1);
    __builtin_amdgcn_s_setprio(1);
#pragma unroll
    for (int i = 0; i < 4; ++i)
#pragma unroll
      for (int j = 2; j < 4; ++j)
        acc[i][j] = __builtin_amdgcn_mfma_f32_16x16x32_bf16(a[i], b[j], acc[i][j], 0, 0, 0);
    __builtin_amdgcn_s_setprio(0);
    // ---- quadrant m1 x n1 ----
#pragma unroll
    for (int i = 4; i < 8; ++i)
      a[i] = *(const short8*)&As_[(arow + i * 16) * 32 + kg8];
    if (st) stageHalf(bufS, t + 2, 2);
    __builtin_amdgcn_s_setprio(1);
#pragma unroll
    for (int i = 4; i < 8; ++i)
#pragma unroll
      for (int j = 2; j < 4; ++j)
        acc[i][j] = __builtin_amdgcn_mfma_f32_16x16x32_bf16(a[i], b[j], acc[i][j], 0, 0, 0);
    __builtin_amdgcn_s_setprio(0);
    // ---- quadrant m1 x n0 (b[0],b[1] still live) ----
    if (st) stageHalf(bufS, t + 2, 3);
    __builtin_amdgcn_s_setprio(1);
#pragma unroll
    for (int i = 4; i < 8; ++i)
#pragma unroll
      for (int j = 0; j < 2; ++j)
        acc[i][j] = __builtin_amdgcn_mfma_f32_16x16x32_bf16(a[i], b[j], acc[i][j], 0, 0, 0);
    __builtin_amdgcn_s_setprio(0);
    buf  = (buf  == 2) ? 0 : buf  + 1;
    bufS = (bufS == 2) ? 0 : bufS + 1;
  }

  // epilogue: C/D col=lane&15, row=(lane>>4)*4+reg (verified layout)
  int rbase = m0 + wm * 128 + (lane >> 4) * 4;
  int cbase = n0 + wn * 64 + (lane & 15);
  bool isg = (n0 < 4096);
#pragma unroll
  for (int mf = 0; mf < 8; ++mf) {
#pragma unroll
    for (int nf = 0; nf < 4; ++nf) {
      int col = cbase + nf * 16;
#pragma unroll
      for (int rr = 0; rr < 4; ++rr) {
        int row = rbase + mf * 16 + rr;
        float v = acc[mf][nf][rr];
        if (isg) Gout[(size_t)row * 4096 + col] = f2bf(v / (1.f + __expf(-v)));
        else     Xout[(size_t)row * 4096 + (col - 4096)] = f2bf(v);
      }
    }
  }
}

// ---------------- bf16 MFMA GEMM, 3-slot ring pipeline (T3+T4+T5) ----------------
// MODE 0: f32 partials (split-K via z); MODE 1: softplus->bf16.
template<int MODE>
__global__ __launch_bounds__(256)
void gemm_bt(const unsigned short* __restrict__ A,
             const unsigned short* __restrict__ B,
             float* __restrict__ C,
             int M, int N, int K, int ksteps_per_z,
             const float* __restrict__ bias,
             unsigned short* __restrict__ out2) {
  __shared__ unsigned short As[3][128 * 32];
  __shared__ unsigned short Bs[3][128 * 32];
  int tid = threadIdx.x;
  int w = tid >> 6, lane = tid & 63;
  int m0 = blockIdx.y * 128, n0 = blockIdx.x * 128;
  int kz0 = blockIdx.z * ksteps_per_z * 32;
  if (MODE == 0) C += (size_t)blockIdx.z * M * N;
  const int NH = ksteps_per_z;

  f32x4 acc[4][4];
#pragma unroll
  for (int i = 0; i < 4; ++i)
#pragma unroll
    for (int j = 0; j < 4; ++j) acc[i][j] = (f32x4){0.f, 0.f, 0.f, 0.f};

  int wm = w >> 1, wn = w & 1;
  int lr = lane & 15, kg = lane >> 4;

  int fe0 = (w) * 512 + lane * 8;
  int fe1 = (4 + w) * 512 + lane * 8;
  int r0 = fe0 >> 5, c0 = fe0 & 31;
  int r1 = fe1 >> 5, c1 = fe1 & 31;
  int sc0 = c0 ^ swzmask(r0);
  int sc1 = c1 ^ swzmask(r1);
  const unsigned short* Ag0 = A + (size_t)(m0 + r0) * K + sc0 + kz0;
  const unsigned short* Ag1 = A + (size_t)(m0 + r1) * K + sc1 + kz0;
  const unsigned short* Bg0 = B + (size_t)(n0 + r0) * K + sc0 + kz0;
  const unsigned short* Bg1 = B + (size_t)(n0 + r1) * K + sc1 + kz0;

  auto stage = [&](int h) {
    int slot = h % 3, kk = h * 32;
    load_lds16(Ag0 + kk, &As[slot][(w) * 512]);
    load_lds16(Ag1 + kk, &As[slot][(4 + w) * 512]);
    load_lds16(Bg0 + kk, &Bs[slot][(w) * 512]);
    load_lds16(Bg1 + kk, &Bs[slot][(4 + w) * 512]);
  };

  stage(0);
  if (NH > 1) stage(1);

  int kgs = (kg * 8) ^ swzmask(lr);

  for (int h = 0; h < NH; ++h) {
    int slot = h % 3;
    __builtin_amdgcn_s_barrier();
    if (h + 2 < NH) stage(h + 2);
    int rem = NH - 1 - h;
    if (rem >= 2)      { asm volatile("s_waitcnt vmcnt(8)" ::: "memory"); }
    else if (rem == 1) { asm volatile("s_waitcnt vmcnt(4)" ::: "memory"); }
    else               { asm volatile("s_waitcnt vmcnt(0)" ::: "memory"); }
    __builtin_amdgcn_s_barrier();
    short8 a[4], b[4];
#pragma unroll
    for (int i = 0; i < 4; ++i)
      a[i] = *(const short8*)&As[slot][(wm * 64 + i * 16 + lr) * 32 + kgs];
#pragma unroll
    for (int j = 0; j < 4; ++j)
      b[j] = *(const short8*)&Bs[slot][(wn * 64 + j * 16 + lr) * 32 + kgs];
    __builtin_amdgcn_s_setprio(1);
#pragma unroll
    for (int i = 0; i < 4; ++i)
#pragma unroll
      for (int j = 0; j < 4; ++j)
        acc[i][j] = __builtin_amdgcn_mfma_f32_16x16x32_bf16(a[i], b[j], acc[i][j], 0, 0, 0);
    __builtin_amdgcn_s_setprio(0);
  }

#pragma unroll
  for (int i = 0; i < 4; ++i) {
#pragma unroll
    for (int j = 0; j < 4; ++j) {
      int rbase = m0 + wm * 64 + i * 16 + kg * 4;
      int col = n0 + wn * 64 + j * 16 + lr;
#pragma unroll
      for (int r = 0; r < 4; ++r) {
        float v = acc[i][j][r];
        if (MODE == 0) {
          C[(size_t)(rbase + r) * N + col] = v;
        } else {
          float t = v + bias[col];
          ((unsigned short*)C)[(size_t)(rbase + r) * N + col] =
              f2bf((t > 20.f) ? t : log1pf(__expf(t)));
        }
      }
    }
  }
  (void)out2;
}

// ---------------- out reduction: out = resid + sum_z part[z]  (2 slices) ----------------
__global__ void reduce_out_kernel(const float* __restrict__ part,
                                  const float* __restrict__ resid,
                                  float* __restrict__ out) {
  size_t base = ((size_t)blockIdx.x * blockDim.x + threadIdx.x) * 4;
  if (base >= (size_t)NBL * ND) return;
  f32x4 r = *(const f32x4*)(resid + base);
#pragma unroll
  for (int z = 0; z < 2; ++z)
    r += *(const f32x4*)(part + (size_t)z * NBL * ND + base);
  *(f32x4*)(out + base) = r;
}

// ---------------- depthwise causal conv (K=4) + SiLU -> bf16 ----------------
__global__ void conv_silu_kernel(const unsigned short* __restrict__ xin,
                                 const float* __restrict__ cw,
                                 const float* __restrict__ cb,
                                 unsigned short* __restrict__ xbf) {
  size_t idx = (size_t)blockIdx.x * blockDim.x + threadIdx.x;
  if (idx >= (size_t)NB * NL * NE) return;
  int e = (int)(idx & (NE - 1));
  int r = (int)(idx >> 12);            // b*NL + l
  int l = r & (NL - 1);
  float acc = cb[e];
#pragma unroll
  for (int k = 0; k < NKC; ++k) {
    int ls = l - 3 + k;
    if (ls >= 0) acc += bf2f(xin[(size_t)(r - 3 + k) * NE + e]) * cw[e * 4 + k];
  }
  float s = acc / (1.f + __expf(-acc));
  xbf[idx] = f2bf(s);
}

// ---------------- reduce split-K partials of the concat GEMM (16 slices) ----------------
__global__ void reduce_tcat_kernel(const float* __restrict__ part,
                                   unsigned short* __restrict__ tbf,
                                   float* __restrict__ bc) {
  int idx = blockIdx.x * blockDim.x + threadIdx.x;
  if (idx >= NBL * 160) return;
  int m = idx / 160, c = idx - m * 160;
  float s = 0.f;
#pragma unroll
  for (int z = 0; z < 16; ++z) s += part[(size_t)z * NBL * 256 + (size_t)m * 256 + c];
  if (c < 128) tbf[m * 128 + c] = f2bf(s);
  else if (c < 144) bc[m * 32 + (c - 128)] = s;
  else bc[m * 32 + 16 + (c - 144)] = s;
}

// ======== selective scan, 4-way L-split, SCAN_T=32, bf16 gate ========
__global__ __launch_bounds__(256)
void scan1_kernel(const unsigned short* __restrict__ delta_bf,
                  const unsigned short* __restrict__ x_bf,
                  const float* __restrict__ bc,
                  const unsigned short* __restrict__ gf,   // bf16 gate
                  const float* __restrict__ A_log,
                  const float* __restrict__ W_D,
                  unsigned short* __restrict__ yg,
                  float* __restrict__ fin,
                  float* __restrict__ dtot) {
  __shared__ unsigned short dxl[2][SCAN_T][2][16];  // 4KB
  __shared__ unsigned short gl[2][SCAN_T][16];      // 2KB (bf16 gate)
  __shared__ float BCl[2][SCAN_T][32];              // 8KB
  __shared__ float yl2[SCAN_T][16][2];              // 4KB
  __shared__ float wdl[16];
  int tid = threadIdx.x;
  int n = tid & 15, el = tid >> 4;
  int w = tid >> 6, lane = tid & 63;
  int e0 = blockIdx.x * 16;
  int b = blockIdx.y >> 2, seg = blockIdx.y & 3;
  int e = e0 + el;
  float A2 = -__expf(A_log[e * 16 + n]) * 1.44269504f;
  if (tid < 16) wdl[tid] = W_D[e0 + tid];
  float h = 0.f, cum = 0.f;

  const unsigned short* gdl = delta_bf + (size_t)b * NL * NE + e0;
  const unsigned short* gx  = x_bf + (size_t)b * NL * NE + e0;
  const unsigned short* gg  = gf + (size_t)b * NL * 4096 + e0;
  const float* gBC = bc + (size_t)b * NL * 32;

  const unsigned short* dxsrc = ((lane >> 1) & 1) ? gx : gdl;  // waves 0,1
  int dxrow = (w & 1) * 16 + (lane >> 2);
  int dxcol = (lane & 1) * 8;
  int grow = lane >> 1;                 // wave 2: full 32-row bf16 chunk (1KB)
  int gcol = (lane & 1) * 8;
  int bcrow = w * 8 + (lane >> 3);      // all waves
  int bccol = (lane & 7) * 4;
  int nloads = (w < 2) ? 2 : ((w == 2 && seg == 0) ? 2 : 1);

  auto stage = [&](int buf, int c) {
    int l0 = seg * SEG_T + c * SCAN_T;
    if (w < 2)
      load_lds16(dxsrc + (size_t)(l0 + dxrow) * NE + dxcol, &dxl[buf][(w & 1) * 16][0][0]);
    else if (w == 2 && seg == 0)
      load_lds16(gg + (size_t)(l0 + grow) * 4096 + gcol, &gl[buf][0][0]);
    load_lds16(gBC + (size_t)(l0 + bcrow) * 32 + bccol, &BCl[buf][w * 8][0]);
  };

  stage(0, 0);
  const int nch = SEG_T / SCAN_T;  // 8
  for (int c = 0; c < nch; ++c) {
    int cur = c & 1;
    if (c + 1 < nch) {
      stage(cur ^ 1, c + 1);
      if (nloads == 2) { asm volatile("s_waitcnt vmcnt(2)" ::: "memory"); }
      else             { asm volatile("s_waitcnt vmcnt(1)" ::: "memory"); }
    } else {
      asm volatile("s_waitcnt vmcnt(0)" ::: "memory");
    }
    __syncthreads();
    const unsigned short (*dxc)[2][16] = dxl[cur];
    const float (*BCc)[32] = BCl[cur];
#pragma unroll 8
    for (int t = 0; t < SCAN_T; ++t) {
      float dc = bf2f(dxc[t][0][el]);
      float xc = bf2f(dxc[t][1][el]);
      float Bc = BCc[t][n];
      float Cc = BCc[t][16 + n];
      cum += dc;
      float a = dc * A2, ed;
      asm("v_exp_f32 %0, %1" : "=v"(ed) : "v"(a));   // exp2(d*A*log2e)
      h = ed * h + (dc * xc) * Bc;
      float p = h * Cc;
      p += dpp_mov<0xB1>(p);    // xor1
      p += dpp_mov<0x4E>(p);    // xor2
      p += dpp_mov<0x141>(p);   // half-mirror -> lanes 0,8 hold 8-group sums
      if ((n & 7) == 0) yl2[t][el][n >> 3] = p;
    }
    __syncthreads();
    {
      int t = tid >> 3, part = tid & 7;   // 2 e's per thread
      int l0 = seg * SEG_T + c * SCAN_T;
      ushort2_t o;
#pragma unroll
      for (int j = 0; j < 2; ++j) {
        int ee = part * 2 + j;
        float xv = bf2f(dxc[t][1][ee]);
        float y = yl2[t][ee][0] + yl2[t][ee][1] + xv * wdl[ee];
        if (seg == 0) y *= bf2f(gl[cur][t][ee]);
        o[j] = f2bf(y);
      }
      *(ushort2_t*)(yg + (size_t)(b * NL + l0 + t) * NE + e0 + part * 2) = o;
    }
    __syncthreads();
  }
  fin[(size_t)((seg * 2 + b) * 4096 + e) * 16 + n] = h;
  if (n == 0) dtot[(size_t)(seg * 2 + b) * 4096 + e] = cum;
}

// K2: fixup for segments 1..3 (bf16 gate)
__global__ __launch_bounds__(256)
void scan2_kernel(const unsigned short* __restrict__ delta_bf,
                  unsigned short* __restrict__ yg,
                  const float* __restrict__ bc,
                  const unsigned short* __restrict__ gf,   // bf16 gate
                  const float* __restrict__ A_log,
                  const float* __restrict__ fin,
                  const float* __restrict__ dtot) {
  __shared__ unsigned short dl[2][SCAN_T][16];      // 2KB
  __shared__ unsigned short ypl[2][SCAN_T][16];     // 2KB
  __shared__ float Cl[2][SCAN_T][16];               // 4KB
  __shared__ unsigned short gl2[2][SCAN_T][16];     // 2KB (bf16 gate)
  __shared__ float ycl[SCAN_T][16][2];              // 4KB
  int tid = threadIdx.x;
  int n = tid & 15, el = tid >> 4;
  int w = tid >> 6, lane = tid & 63;
  int e0 = blockIdx.x * 16;
  int b = blockIdx.y / 3, seg = 1 + blockIdx.y % 3;
  int e = e0 + el;
  float A2 = -__expf(A_log[e * 16 + n]) * 1.44269504f;
  float h = fin[(size_t)(b * 4096 + e) * 16 + n];           // seg 0 final
  for (int s2 = 1; s2 < seg; ++s2) {
    float dt = dtot[(size_t)(s2 * 2 + b) * 4096 + e];
    float a = A2 * dt, pw;
    asm("v_exp_f32 %0, %1" : "=v"(pw) : "v"(a));
    h = fin[(size_t)((s2 * 2 + b) * 4096 + e) * 16 + n] + pw * h;
  }

  const unsigned short* gd = delta_bf + (size_t)b * NL * NE + e0;
  unsigned short* gy = yg + (size_t)b * NL * NE + e0;
  const unsigned short* gg  = gf + (size_t)b * NL * 4096 + e0;
  const float* gBC = bc + (size_t)b * NL * 32;

  int dyrow = lane >> 1;
  int dycol = (lane & 1) * 8;
  int crow = (w & 1) * 16 + (lane >> 2);
  int ccol = 16 + (lane & 3) * 4;
  int grow = lane >> 1;                 // wave 2: full 32-row bf16 chunk
  int gcol = (lane & 1) * 8;
  int nloads = (w < 2) ? 2 : ((w == 2) ? 1 : 0);

  auto stage = [&](int buf, int c) {
    int l0 = seg * SEG_T + c * SCAN_T;
    if (w == 0)      load_lds16(gd + (size_t)(l0 + dyrow) * NE + dycol, &dl[buf][0][0]);
    else if (w == 1) load_lds16(gy + (size_t)(l0 + dyrow) * NE + dycol, &ypl[buf][0][0]);
    if (w < 2) load_lds16(gBC + (size_t)(l0 + crow) * 32 + ccol, &Cl[buf][(w & 1) * 16][0]);
    else if (w == 2) load_lds16(gg + (size_t)(l0 + grow) * 4096 + gcol, &gl2[buf][0][0]);
  };

  stage(0, 0);
  float cum = 0.f;
  const int nch = SEG_T / SCAN_T;  // 8
  for (int c = 0; c < nch; ++c) {
    int cur = c & 1;
    if (c + 1 < nch) {
      stage(cur ^ 1, c + 1);
      if (nloads == 2)      { asm volatile("s_waitcnt vmcnt(2)" ::: "memory"); }
      else if (nloads == 1) { asm volatile("s_waitcnt vmcnt(1)" ::: "memory"); }
      else                  { asm volatile("s_waitcnt vmcnt(0)" ::: "memory"); }
    } else {
      asm volatile("s_waitcnt vmcnt(0)" ::: "memory");
    }
    __syncthreads();
    const unsigned short (*dc_)[16] = dl[cur];
    const float (*Cc_)[16] = Cl[cur];
#pragma unroll 8
    for (int t = 0; t < SCAN_T; ++t) {
      float dcv = bf2f(dc_[t][el]);
      cum += dcv;
      float a = A2 * cum, pw;
      asm("v_exp_f32 %0, %1" : "=v"(pw) : "v"(a));
      float p = (pw * h) * Cc_[t][n];
      p += dpp_mov<0xB1>(p);
      p += dpp_mov<0x4E>(p);
      p += dpp_mov<0x141>(p);
      if ((n & 7) == 0) ycl[t][el][n >> 3] = p;
    }
    __syncthreads();
    {
      int t = tid >> 3, part = tid & 7;
      int l0 = seg * SEG_T + c * SCAN_T;
      ushort2_t o;
#pragma unroll
      for (int j = 0; j < 2; ++j) {
        int ee = part * 2 + j;
        float y = ycl[t][ee][0] + ycl[t][ee][1] + bf2f(ypl[cur][t][ee]);
        o[j] = f2bf(y * bf2f(gl2[cur][t][ee]));
      }
      *(ushort2_t*)(gy + (size_t)(l0 + t) * NE + part * 2) = o;
    }
    __syncthreads();
  }
}

// ---------------- host launcher ----------------
extern "C" void kernel_launch(void* const* d_in, const int* in_sizes, int n_in,
                              void* d_out, int out_size, void* d_ws, size_t ws_size,
                              hipStream_t stream) {
  const float* resid  = (const float*)d_in[0];
  const float* norm_w = (const float*)d_in[1];
  const float* skip_w = (const float*)d_in[2];
  const float* in_w   = (const float*)d_in[3];
  const float* conv_w = (const float*)d_in[4];
  const float* conv_b = (const float*)d_in[5];
  const float* wd1    = (const float*)d_in[6];
  const float* wd2    = (const float*)d_in[7];
  const float* wd2_b  = (const float*)d_in[8];
  const float* wB     = (const float*)d_in[9];
  const float* wC     = (const float*)d_in[10];
  const float* A_log  = (const float*)d_in[11];
  const float* W_D    = (const float*)d_in[12];
  const float* out_w  = (const float*)d_in[13];
  float* out = (float*)d_out;

  char* ws = (char*)d_ws;
  size_t off = 0;
  auto alloc = [&](size_t bytes) -> void* {
    void* p = ws + off;
    off += (bytes + 255) & ~(size_t)255;
    return p;
  };
  unsigned short* rn_bf      = (unsigned short*)alloc((size_t)NBL * ND * 2);
  unsigned short* wskipin_bf = (unsigned short*)alloc((size_t)2 * NE * ND * 2);  // [skip_w; in_w]
  unsigned short* wout_bf    = (unsigned short*)alloc((size_t)ND * NE * 2);
  unsigned short* wd2_bf     = (unsigned short*)alloc((size_t)NE * NR * 2);
  unsigned short* wcat_bf    = (unsigned short*)alloc((size_t)256 * NE * 2);
  unsigned short* g_bf       = (unsigned short*)alloc((size_t)NBL * NE * 2);  // silu(skip) bf16 16.78MB
  unsigned short* xin_bf     = (unsigned short*)alloc((size_t)NBL * NE * 2);  // 16.78MB
  unsigned short* x_bf       = (unsigned short*)alloc((size_t)NBL * NE * 2);  // 16.78MB
  float* part_f              = (float*)alloc((size_t)16 * NBL * 256 * 4);
  unsigned short* t_bf       = (unsigned short*)alloc((size_t)NBL * NR * 2);
  float* bc_f                = (float*)alloc((size_t)NBL * 32 * 4);
  unsigned short* yg_bf      = (unsigned short*)alloc((size_t)NBL * NE * 2);
  float* fin_f               = (float*)alloc((size_t)4 * NB * NE * 16 * 4);
  float* dtot_f              = (float*)alloc((size_t)4 * NB * NE * 4);
  // delta (bf16) aliases wskipin_bf (consumed by step 3, rewritten each replay).
  unsigned short* delta_bf = wskipin_bf;
  // out-GEMM split-K=2 partials (2 x 16.78MB = 33.55MB) alias g_bf+xin_bf
  // (contiguous, both dead after scan2 -> stream-ordered safe).
  float* part2_f = (float*)g_bf;
  (void)ws_size; (void)in_sizes; (void)n_in; (void)out_size;

  // 1. RMSNorm -> rn bf16
  rmsnorm_kernel<<<dim3(NBL), dim3(256), 0, stream>>>(resid, norm_w, rn_bf);

  // 2. weight casts
  cast_bf16_kernel<<<dim3((NE * ND / 8 + 255) / 256), dim3(256), 0, stream>>>(skip_w, wskipin_bf, NE * ND / 8);
  cast_bf16_kernel<<<dim3((NE * ND / 8 + 255) / 256), dim3(256), 0, stream>>>(in_w, wskipin_bf + (size_t)NE * ND, NE * ND / 8);
  cast_bf16_kernel<<<dim3((ND * NE / 8 + 255) / 256), dim3(256), 0, stream>>>(out_w, wout_bf, ND * NE / 8);
  cast_bf16_kernel<<<dim3((NE * NR / 8 + 255) / 256), dim3(256), 0, stream>>>(wd2, wd2_bf, NE * NR / 8);
  build_wcat_kernel<<<dim3(256 * NE / 8 / 256), dim3(256), 0, stream>>>(wd1, wB, wC, wcat_bf);

  // 3. fused [g|xin] = rn @ [skip_w; in_w]^T  (256^2 ring + XCD remap, bf16 g)
  gemm256_fused<<<dim3(8192 / 256, NBL / 256), dim3(512), 0, stream>>>(
      rn_bf, wskipin_bf, g_bf, xin_bf);

  // 5. conv + silu -> x_bf
  conv_silu_kernel<<<dim3((int)(((size_t)NB * NL * NE) / 256)), dim3(256), 0, stream>>>(
      xin_bf, conv_w, conv_b, x_bf);

  // 6. tcat = x @ [wd1;wB;wC]^T  split-K=16 -> partials
  gemm_bt<0><<<dim3(256 / 128, NBL / 128, 16), dim3(256), 0, stream>>>(
      x_bf, wcat_bf, part_f, NBL, 256, NE, (NE / 32) / 16, nullptr, nullptr);
  // 7. reduce partials -> t_bf, bc (interleaved B|C)
  reduce_tcat_kernel<<<dim3((NBL * 160 + 255) / 256), dim3(256), 0, stream>>>(
      part_f, t_bf, bc_f);

  // 8. delta = softplus(t @ wd2^T + wd2_b) -> bf16  [2048,4096] k=128
  gemm_bt<1><<<dim3(NE / 128, NBL / 128, 1), dim3(256), 0, stream>>>(
      t_bf, wd2_bf, (float*)delta_bf, NBL, NE, NR, NR / 32, wd2_b, nullptr);

  // 9a. segment-local scans (4-way L-split)
  scan1_kernel<<<dim3(NE / 16, NB * 4), dim3(256), 0, stream>>>(
      delta_bf, x_bf, bc_f, g_bf, A_log, W_D, yg_bf, fin_f, dtot_f);
  // 9b. fixup segments 1..3 (+ gating)
  scan2_kernel<<<dim3(NE / 16, NB * 3), dim3(256), 0, stream>>>(
      delta_bf, yg_bf, bc_f, g_bf, A_log, fin_f, dtot_f);

  // 10a. out partials = yg @ out_w^T  split-K=2  [2048,2048] k=2048 each
  gemm_bt<0><<<dim3(ND / 128, NBL / 128, 2), dim3(256), 0, stream>>>(
      yg_bf, wout_bf, part2_f, NBL, ND, NE, (NE / 32) / 2, nullptr, nullptr);
  // 10b. out = resid + sum partials
  reduce_out_kernel<<<dim3((int)((size_t)NBL * ND / 4 / 256)), dim3(256), 0, stream>>>(
      part2_f, resid, out);
}